// Round 2
// baseline (1116.048 us; speedup 1.0000x reference)
//
#include <hip/hip_runtime.h>
#include <cstdint>
#include <cstddef>

#define N_TOK 4096
#define DIM   1024
#define NEXP  8
#define HID   4096
#define TWO_H 8192
#define CAP   1280

typedef __bf16 bf16x8 __attribute__((ext_vector_type(8)));
typedef float  f32x4  __attribute__((ext_vector_type(4)));

__device__ __forceinline__ unsigned short f2bf(float f) {
  union { float f; unsigned u; } v; v.f = f;
  unsigned r = v.u + 0x7FFF + ((v.u >> 16) & 1);   // RNE
  return (unsigned short)(r >> 16);
}
__device__ __forceinline__ float bf2f(unsigned short b) {
  union { unsigned u; float f; } v; v.u = ((unsigned)b) << 16;
  return v.f;
}

// async global->LDS DMA, 16B per lane; LDS dest = wave-uniform base + lane*16
__device__ __forceinline__ void gll16(const unsigned short* g, unsigned short* l) {
  __builtin_amdgcn_global_load_lds(
      (const __attribute__((address_space(1))) uint32_t*)g,
      (__attribute__((address_space(3))) uint32_t*)l, 16, 0, 0);
}

// ---------------- zero accumulators ----------------
__global__ void k_zero(float* imp, float* zsum) {
  if (threadIdx.x < NEXP) imp[threadIdx.x] = 0.f;
  if (threadIdx.x == 0) zsum[0] = 0.f;
}

// ---------------- W1 [E][D][2H] fp32 -> packed W1t [E][2H][D] bf16 ----------------
__global__ void k_conv_w1(const float* __restrict__ W1, unsigned short* __restrict__ W1t) {
  __shared__ float tA[32][33];
  __shared__ float tG[32][33];
  int h0 = blockIdx.x * 32, d0 = blockIdx.y * 32, e = blockIdx.z;
  int tx = threadIdx.x & 31, ty = threadIdx.x >> 5;  // ty 0..7
  const float* src = W1 + (size_t)e * DIM * TWO_H;
  for (int i = 0; i < 32; i += 8) {
    int d = d0 + ty + i;
    tA[ty + i][tx] = src[(size_t)d * TWO_H + h0 + tx];
    tG[ty + i][tx] = src[(size_t)d * TWO_H + HID + h0 + tx];
  }
  __syncthreads();
  unsigned short* dst = W1t + (size_t)e * TWO_H * DIM;
  for (int i = 0; i < 64; i += 8) {
    int r = ty + i;                  // 0..63 local packed row
    int hh = r >> 1, p = r & 1;
    float v = p ? tG[tx][hh] : tA[tx][hh];
    dst[(size_t)(2 * h0 + r) * DIM + d0 + tx] = f2bf(v);
  }
}

// ---------------- W2 [E][H][D] fp32 -> W2t [E][D][H] bf16 ----------------
__global__ void k_conv_w2(const float* __restrict__ W2, unsigned short* __restrict__ W2t) {
  __shared__ float t[32][33];
  int d0 = blockIdx.x * 32, h0 = blockIdx.y * 32, e = blockIdx.z;
  int tx = threadIdx.x & 31, ty = threadIdx.x >> 5;
  const float* src = W2 + (size_t)e * HID * DIM;
  for (int i = 0; i < 32; i += 8)
    t[ty + i][tx] = src[(size_t)(h0 + ty + i) * DIM + d0 + tx];
  __syncthreads();
  unsigned short* dst = W2t + (size_t)e * DIM * HID;
  for (int i = 0; i < 32; i += 8)
    dst[(size_t)(d0 + ty + i) * HID + h0 + tx] = f2bf(t[tx][ty + i]);
}

// ---------------- b1 [E][2H] -> packed b1p [E][2H] (pairs a,g) ----------------
__global__ void k_pack_b1(const float* __restrict__ b1, float* __restrict__ b1p) {
  int g = blockIdx.x * blockDim.x + threadIdx.x;
  int e = g >> 13, r = g & (TWO_H - 1);
  int h = r >> 1, p = r & 1;
  b1p[g] = b1[e * TWO_H + p * HID + h];
}

// ---------------- router v2: 16 tokens/block, block-local reduction ----------------
__global__ void __launch_bounds__(256) k_router(
    const float* __restrict__ x, const float* __restrict__ Wr, const float* __restrict__ br,
    int* __restrict__ idx, float* __restrict__ gate,
    float* __restrict__ imp, float* __restrict__ zsum) {
  __shared__ float sW[TWO_H];          // 32 KB  (Wr is [D][E] = 1024*8)
  __shared__ float sX[16 * 1028];      // 65.8 KB
  __shared__ float sLG[16 * 8];
  __shared__ float sImp[8];
  __shared__ float sZ;
  int tid = threadIdx.x;
  if (tid < 8) sImp[tid] = 0.f;
  if (tid == 8) sZ = 0.f;
  for (int i = 0; i < 8; ++i) {
    int g = tid + i * 256;
    *(float4*)&sW[g * 4] = *(const float4*)&Wr[g * 4];
  }
  int t0 = blockIdx.x * 16;
  const float* xb = x + (size_t)t0 * DIM;
  for (int i = 0; i < 16; ++i) {
    int g = tid + i * 256;           // global float4 index within 16 rows
    int row = g >> 8, c = (g & 255) * 4;
    *(float4*)&sX[row * 1028 + c] = *(const float4*)&xb[(size_t)g * 4];
  }
  __syncthreads();
  int t = tid >> 4, e = (tid >> 1) & 7, half = tid & 1;
  const float* xr = &sX[t * 1028 + half * 512];
  float s = 0.f;
  for (int k = 0; k < 512; k += 4) {
    float4 xv = *(const float4*)&xr[k];
    int kb = (half * 512 + k) * 8 + e;
    s += xv.x * sW[kb] + xv.y * sW[kb + 8] + xv.z * sW[kb + 16] + xv.w * sW[kb + 24];
  }
  s += __shfl_xor(s, 1);               // combine the two K-halves
  if (half == 0) sLG[t * 8 + e] = s + br[e];
  __syncthreads();
  if (tid < 16) {
    int n = t0 + tid;
    float lg[8];
    for (int i = 0; i < 8; ++i) lg[i] = sLG[tid * 8 + i];
    float mx = lg[0];
    for (int i = 1; i < 8; ++i) mx = fmaxf(mx, lg[i]);
    float ex[8], den = 0.f, zs = 0.f;
    for (int i = 0; i < 8; ++i) { ex[i] = __expf(lg[i] - mx); den += ex[i]; zs += lg[i] * lg[i]; }
    atomicAdd(&sZ, zs);
    float rden = 1.f / den;
    for (int i = 0; i < 8; ++i) atomicAdd(&sImp[i], ex[i] * rden);
    int i1 = 0;
    for (int i = 1; i < 8; ++i) if (lg[i] > lg[i1]) i1 = i;     // ties -> lowest idx, like top_k
    int i2 = -1;
    for (int i = 0; i < 8; ++i) { if (i == i1) continue; if (i2 < 0 || lg[i] > lg[i2]) i2 = i; }
    float e2 = __expf(lg[i2] - lg[i1]);
    float g1 = 1.f / (1.f + e2);
    idx[n * 2] = i1; idx[n * 2 + 1] = i2;
    gate[n * 2] = g1; gate[n * 2 + 1] = 1.f - g1;
  }
  __syncthreads();
  if (tid < 8) atomicAdd(&imp[tid], sImp[tid]);
  if (tid == 8) atomicAdd(zsum, sZ);
}

// ---------------- per-expert sequential position scan (flat order s = k*N + n) -----
__global__ void k_scan(const int* __restrict__ idx, int* __restrict__ pos, int* __restrict__ cnt) {
  int wave = threadIdx.x >> 6, lane = threadIdx.x & 63;  // wave == expert id
  int base = 0;
  for (int c = 0; c < (2 * N_TOK) / 64; ++c) {
    int s = c * 64 + lane;
    int n = s & (N_TOK - 1), k = s >> 12;
    int e = idx[n * 2 + k];
    unsigned long long m = __ballot(e == wave);
    if (e == wave) pos[s] = base + __popcll(m & ((1ull << lane) - 1ull));
    base += __popcll(m);
  }
  if (lane == 0) cnt[wave] = base;
}

// ---------------- renormalized kept gates ----------------
__global__ void k_weights(const float* __restrict__ gate, const int* __restrict__ pos,
                          float* __restrict__ wn) {
  int n = blockIdx.x * blockDim.x + threadIdx.x;
  if (n >= N_TOK) return;
  float g0 = gate[n * 2], g1 = gate[n * 2 + 1];
  float k0 = (pos[n] < CAP) ? g0 : 0.f;
  float k1 = (pos[N_TOK + n] < CAP) ? g1 : 0.f;
  float den = fmaxf(k0 + k1, 1e-8f);
  wn[n * 2] = k0 / den; wn[n * 2 + 1] = k1 / den;
}

// ---------------- gather + per-expert LayerNorm -> Xn bf16 [E][CAP][D] ----------------
__global__ void __launch_bounds__(256) k_gather_ln(
    const float* __restrict__ x, const float* __restrict__ lns, const float* __restrict__ lnb,
    const int* __restrict__ idx, const int* __restrict__ pos, unsigned short* __restrict__ Xn) {
  int s = blockIdx.x;
  int p = pos[s];
  if (p >= CAP) return;                       // dropped slot (block-uniform exit)
  int n = s & (N_TOK - 1), k = s >> 12;
  int e = idx[n * 2 + k];
  const float* xr = x + (size_t)n * DIM;
  int tid = threadIdx.x;
  float v[4], sum = 0.f, sq = 0.f;
  for (int i = 0; i < 4; ++i) { v[i] = xr[tid + i * 256]; sum += v[i]; sq += v[i] * v[i]; }
  for (int o = 32; o > 0; o >>= 1) { sum += __shfl_down(sum, o); sq += __shfl_down(sq, o); }
  __shared__ float ws[8];
  int wv = tid >> 6, ln = tid & 63;
  if (ln == 0) { ws[wv] = sum; ws[4 + wv] = sq; }
  __syncthreads();
  sum = ws[0] + ws[1] + ws[2] + ws[3];
  sq  = ws[4] + ws[5] + ws[6] + ws[7];
  float mu = sum * (1.f / DIM);
  float var = sq * (1.f / DIM) - mu * mu;
  float rs = rsqrtf(var + 1e-5f);
  unsigned short* orow = Xn + ((size_t)e * CAP + p) * DIM;
  const float* sc = lns + (size_t)e * DIM;
  const float* bi = lnb + (size_t)e * DIM;
  for (int i = 0; i < 4; ++i) {
    int d = tid + i * 256;
    orow[d] = f2bf((v[i] - mu) * rs * sc[d] + bi[d]);
  }
}

// ---------------- bf16 MFMA GEMM: C[m][n] = sum_k A[m][k] * B[n][k]  (B is N-major, B^T) ----
// R2: m97 structure — global_load_lds width=16 into LINEAR [128][64] LDS tiles
// (reg-staging measured 646 vs 874 TF in m151; compiler never auto-emits the DMA).
// Linear layout is REQUIRED by global_load_lds (dest = wave-uniform base + lane*16).
// R2: T1 bijective XCD swizzle (both grids nwg%8==0). Each XCD gets a contiguous
// logical chunk ~= one expert: A (2.6 MB/expert) L2-resident; each B n-panel served
// from ONE XCD's L2 instead of 8. Predicted FETCH 620 MB -> ~200-250 MB.
template<bool GLU>
__global__ void __launch_bounds__(256) k_gemm(
    const unsigned short* __restrict__ A,   // [E][M][K]
    const unsigned short* __restrict__ B,   // [E][Nn][K]
    const float* __restrict__ bias,         // b1p [E][2H] (only used if GLU)
    unsigned short* __restrict__ Cout,      // GLU: [E][M][Nn/2] else [E][M][Nn]
    int M, int Nn, int K) {
  // sA/sB: 2 x 128x64 shorts = 32 KB; epilogue staging needs up to 128*136 shorts
  __shared__ __align__(16) unsigned short smem[17408];   // 34.8 KB
  unsigned short* sA = smem;              // [128][64] linear
  unsigned short* sB = smem + 128 * 64;   // [128][64] linear

  // T1 XCD swizzle: physical bid -> logical lid; contiguous lid chunk per XCD
  int gx = gridDim.x, gy = gridDim.y;
  int nwg = gx * gy * (int)gridDim.z;
  int bid = blockIdx.x + gx * (blockIdx.y + gy * blockIdx.z);
  int lid = (bid & 7) * (nwg >> 3) + (bid >> 3);
  int bm = lid % gx; int rest = lid / gx;
  int e  = rest / gy;
  int m0 = bm * 128, n0 = (rest % gy) * 128;

  const unsigned short* Ae = A + (size_t)e * M * K;
  const unsigned short* Be = B + (size_t)e * Nn * K;
  int tid = threadIdx.x;
  int lane = tid & 63, wave = tid >> 6;
  int wm = (wave >> 1) * 64, wn = (wave & 1) * 64;
  int quad = lane >> 4, l16 = lane & 15;
  f32x4 acc[4][4];
  for (int i = 0; i < 4; ++i)
    for (int j = 0; j < 4; ++j) acc[i][j] = f32x4{0.f, 0.f, 0.f, 0.f};

  // staging geometry: wave w owns rows [w*32, w*32+32); per call one wave DMAs
  // 8 rows x 128B (lane = 8*row + chunk); 4 calls each for A and B per K-step
  int srr = lane >> 3;          // row within 8-row group
  int scc = lane & 7;           // 16B chunk within row
  const unsigned short* Ag = Ae + (size_t)(m0 + wave * 32 + srr) * K + scc * 8;
  const unsigned short* Bg = Be + (size_t)(n0 + wave * 32 + srr) * K + scc * 8;
  unsigned short* sAw = sA + wave * (32 * 64);
  unsigned short* sBw = sB + wave * (32 * 64);

  for (int k0 = 0; k0 < K; k0 += 64) {
    __syncthreads();                       // prev compute done before overwrite
    for (int c = 0; c < 4; ++c) {
      gll16(Ag + (size_t)(c * 8) * K + k0, sAw + c * (8 * 64));
      gll16(Bg + (size_t)(c * 8) * K + k0, sBw + c * (8 * 64));
    }
    __syncthreads();                       // compiler drains vmcnt(0) before barrier
    for (int kk = 0; kk < 64; kk += 32) {
      bf16x8 aF[4], bF[4];
      for (int i = 0; i < 4; ++i) {
        aF[i] = *(const bf16x8*)&sA[(wm + i * 16 + l16) * 64 + kk + quad * 8];
        bF[i] = *(const bf16x8*)&sB[(wn + i * 16 + l16) * 64 + kk + quad * 8];
      }
      for (int i = 0; i < 4; ++i)
        for (int j = 0; j < 4; ++j)
          acc[i][j] = __builtin_amdgcn_mfma_f32_16x16x32_bf16(aF[i], bF[j], acc[i][j], 0, 0, 0);
    }
  }
  __syncthreads();   // K-loop LDS reads done in all waves; smem is reused below
  if (GLU) {
    const float* bp = bias + (size_t)e * TWO_H;
    unsigned short* Ce = Cout + (size_t)e * M * (Nn >> 1);
    // stage packed GLU output tile: [128 rows][64 shorts], row stride 80 (160B, 16B-mult)
    for (int i = 0; i < 4; ++i)
      for (int j = 0; j < 4; ++j) {
        int pn = n0 + wn + j * 16 + l16;
        float b = bp[pn];
        for (int r = 0; r < 4; ++r) {
          int row = wm + i * 16 + quad * 4 + r;
          float u = acc[i][j][r] + b;          // includes bias for both a and g lanes
          float g = __shfl_xor(u, 1);          // partner column (pn^1)
          if ((l16 & 1) == 0) {                // even col = a, partner = g
            float vv = u / (1.f + __expf(-g));
            smem[row * 80 + ((wn + j * 16 + l16) >> 1)] = f2bf(vv);
          }
        }
      }
    __syncthreads();
    // cooperative coalesced store: 64 shorts (128B) per row, 8 lanes x int4
    int c = tid & 7, row0 = tid >> 3;
    for (int p = 0; p < 4; ++p) {
      int row = row0 + p * 32;
      *(int4*)&Ce[(size_t)(m0 + row) * (Nn >> 1) + (n0 >> 1) + c * 8] =
          *(const int4*)&smem[row * 80 + c * 8];
    }
  } else {
    unsigned short* Ce = Cout + (size_t)e * M * Nn;
    // stage output tile: [128 rows][128 shorts], row stride 136 (272B, 16B-mult)
    for (int i = 0; i < 4; ++i)
      for (int j = 0; j < 4; ++j) {
        int col = wn + j * 16 + l16;
        for (int r = 0; r < 4; ++r) {
          int row = wm + i * 16 + quad * 4 + r;
          smem[row * 136 + col] = f2bf(acc[i][j][r]);
        }
      }
    __syncthreads();
    // cooperative coalesced store: 128 shorts (256B) per row, 16 lanes x int4
    int c = tid & 15, row0 = tid >> 4;
    for (int p = 0; p < 8; ++p) {
      int row = row0 + p * 16;
      *(int4*)&Ce[(size_t)(m0 + row) * Nn + n0 + c * 8] =
          *(const int4*)&smem[row * 136 + c * 8];
    }
  }
}

// ---------------- combine: y[n] = sum_k w_k * (Yexp[e_k][p_k] + b2[e_k]) ----------------
__global__ void __launch_bounds__(256) k_gather_out(
    const unsigned short* __restrict__ Yexp, const float* __restrict__ b2,
    const int* __restrict__ idx, const int* __restrict__ pos,
    const float* __restrict__ wn, float* __restrict__ y) {
  int n = blockIdx.x, tid = threadIdx.x;
  int e0 = idx[n * 2], e1 = idx[n * 2 + 1];
  int p0 = min(pos[n], CAP - 1), p1 = min(pos[N_TOK + n], CAP - 1);
  float w0 = wn[n * 2], w1 = wn[n * 2 + 1];
  const unsigned short* r0 = Yexp + ((size_t)e0 * CAP + p0) * DIM;
  const unsigned short* r1 = Yexp + ((size_t)e1 * CAP + p1) * DIM;
  const float* bb0 = b2 + (size_t)e0 * DIM;
  const float* bb1 = b2 + (size_t)e1 * DIM;
  float* yr = y + (size_t)n * DIM;
  for (int i = 0; i < 4; ++i) {
    int d = tid + i * 256;
    yr[d] = w0 * (bf2f(r0[d]) + bb0[d]) + w1 * (bf2f(r1[d]) + bb1[d]);
  }
}

// ---------------- scalar losses ----------------
__global__ void k_losses(const float* __restrict__ imp, const int* __restrict__ cnt,
                         const float* __restrict__ zsum, float* __restrict__ out) {
  if (threadIdx.x != 0 || blockIdx.x != 0) return;
  double li[8], ll[8], mi = 0.0, ml = 0.0;
  for (int i = 0; i < 8; ++i) {
    li[i] = imp[i];
    ll[i] = (double)min(cnt[i], CAP);
    mi += li[i]; ml += ll[i];
  }
  mi /= 8.0; ml /= 8.0;
  double vi = 0.0, vl = 0.0;
  for (int i = 0; i < 8; ++i) { vi += (li[i] - mi) * (li[i] - mi); vl += (ll[i] - ml) * (ll[i] - ml); }
  vi /= 8.0; vl /= 8.0;
  const double eps = 1e-9;
  double cvi = vi / (fmax(mi, eps) * fmax(mi, eps) + eps);
  double cvl = vl / (fmax(ml, eps) * fmax(ml, eps) + eps);
  out[0] = (float)(0.5 * (cvi + cvl));
  out[1] = (float)((double)zsum[0] / (double)(N_TOK * NEXP) * 1e-4);
}

extern "C" void kernel_launch(void* const* d_in, const int* in_sizes, int n_in,
                              void* d_out, int out_size, void* d_ws, size_t ws_size,
                              hipStream_t stream) {
  const float* h   = (const float*)d_in[0];
  const float* Wr  = (const float*)d_in[1];
  const float* br  = (const float*)d_in[2];
  const float* lns = (const float*)d_in[3];
  const float* lnb = (const float*)d_in[4];
  const float* W1  = (const float*)d_in[5];
  const float* b1  = (const float*)d_in[6];
  const float* W2  = (const float*)d_in[7];
  const float* b2  = (const float*)d_in[8];
  float* out = (float*)d_out;

  char* ws = (char*)d_ws;
  size_t off = 0;
  auto alloc = [&](size_t bytes) { char* p = ws + off; off += (bytes + 255) & ~(size_t)255; return p; };
  unsigned short* W1t = (unsigned short*)alloc((size_t)NEXP * TWO_H * DIM * 2);  // 134 MB
  unsigned short* W2t = (unsigned short*)alloc((size_t)NEXP * DIM * HID * 2);    // 67 MB
  unsigned short* Xn  = (unsigned short*)alloc((size_t)NEXP * CAP * DIM * 2);    // 21 MB
  unsigned short* V   = (unsigned short*)alloc((size_t)NEXP * CAP * HID * 2);    // 84 MB
  unsigned short* Yx  = (unsigned short*)alloc((size_t)NEXP * CAP * DIM * 2);    // 21 MB
  float* b1p  = (float*)alloc((size_t)NEXP * TWO_H * 4);
  int*   idx  = (int*)alloc((size_t)N_TOK * 2 * 4);
  float* gate = (float*)alloc((size_t)N_TOK * 2 * 4);
  float* wn   = (float*)alloc((size_t)N_TOK * 2 * 4);
  int*   pos  = (int*)alloc((size_t)2 * N_TOK * 4);
  int*   cnt  = (int*)alloc(64);
  float* imp  = (float*)alloc(64);
  float* zsum = (float*)alloc(64);
  (void)ws_size; (void)in_sizes; (void)n_in; (void)out_size;

  k_zero<<<dim3(1), dim3(64), 0, stream>>>(imp, zsum);
  k_conv_w1<<<dim3(HID / 32, DIM / 32, NEXP), dim3(256), 0, stream>>>(W1, W1t);
  k_conv_w2<<<dim3(DIM / 32, HID / 32, NEXP), dim3(256), 0, stream>>>(W2, W2t);
  k_pack_b1<<<dim3(NEXP * TWO_H / 256), dim3(256), 0, stream>>>(b1, b1p);
  k_router<<<dim3(N_TOK / 16), dim3(256), 0, stream>>>(h, Wr, br, idx, gate, imp, zsum);
  k_scan<<<dim3(1), dim3(512), 0, stream>>>(idx, pos, cnt);
  k_weights<<<dim3(16), dim3(256), 0, stream>>>(gate, pos, wn);
  k_gather_ln<<<dim3(2 * N_TOK), dim3(256), 0, stream>>>(h, lns, lnb, idx, pos, Xn);
  k_gemm<true><<<dim3(CAP / 128, TWO_H / 128, NEXP), dim3(256), 0, stream>>>(
      Xn, W1t, b1p, V, CAP, TWO_H, DIM);
  k_gemm<false><<<dim3(CAP / 128, DIM / 128, NEXP), dim3(256), 0, stream>>>(
      V, W2t, b1p, Yx, CAP, DIM, HID);
  k_gather_out<<<dim3(N_TOK), dim3(256), 0, stream>>>(Yx, b2, idx, pos, wn, out);
  k_losses<<<dim3(1), dim3(64), 0, stream>>>(imp, cnt, zsum, out + (size_t)N_TOK * DIM);
}

// Round 3
// 928.835 us; speedup vs baseline: 1.2016x; 1.2016x over previous
//
#include <hip/hip_runtime.h>
#include <cstdint>
#include <cstddef>

#define N_TOK 4096
#define DIM   1024
#define NEXP  8
#define HID   4096
#define TWO_H 8192
#define CAP   1280

typedef __bf16 bf16x8 __attribute__((ext_vector_type(8)));
typedef float  f32x4  __attribute__((ext_vector_type(4)));

__device__ __forceinline__ unsigned short f2bf(float f) {
  union { float f; unsigned u; } v; v.f = f;
  unsigned r = v.u + 0x7FFF + ((v.u >> 16) & 1);   // RNE
  return (unsigned short)(r >> 16);
}
__device__ __forceinline__ float bf2f(unsigned short b) {
  union { unsigned u; float f; } v; v.u = ((unsigned)b) << 16;
  return v.f;
}

// async global->LDS DMA, 16B per lane; LDS dest = wave-uniform base + lane*16
__device__ __forceinline__ void gll16(const unsigned short* g, unsigned short* l) {
  __builtin_amdgcn_global_load_lds(
      (const __attribute__((address_space(1))) uint32_t*)g,
      (__attribute__((address_space(3))) uint32_t*)l, 16, 0, 0);
}

// ---------------- zero accumulators ----------------
__global__ void k_zero(float* imp, float* zsum) {
  if (threadIdx.x < NEXP) imp[threadIdx.x] = 0.f;
  if (threadIdx.x == 0) zsum[0] = 0.f;
}

// ---------------- W1 [E][D][2H] fp32 -> packed W1t [E][2H][D] bf16 ----------------
__global__ void k_conv_w1(const float* __restrict__ W1, unsigned short* __restrict__ W1t) {
  __shared__ float tA[32][33];
  __shared__ float tG[32][33];
  int h0 = blockIdx.x * 32, d0 = blockIdx.y * 32, e = blockIdx.z;
  int tx = threadIdx.x & 31, ty = threadIdx.x >> 5;  // ty 0..7
  const float* src = W1 + (size_t)e * DIM * TWO_H;
  for (int i = 0; i < 32; i += 8) {
    int d = d0 + ty + i;
    tA[ty + i][tx] = src[(size_t)d * TWO_H + h0 + tx];
    tG[ty + i][tx] = src[(size_t)d * TWO_H + HID + h0 + tx];
  }
  __syncthreads();
  unsigned short* dst = W1t + (size_t)e * TWO_H * DIM;
  for (int i = 0; i < 64; i += 8) {
    int r = ty + i;                  // 0..63 local packed row
    int hh = r >> 1, p = r & 1;
    float v = p ? tG[tx][hh] : tA[tx][hh];
    dst[(size_t)(2 * h0 + r) * DIM + d0 + tx] = f2bf(v);
  }
}

// ---------------- W2 [E][H][D] fp32 -> W2t [E][D][H] bf16 ----------------
__global__ void k_conv_w2(const float* __restrict__ W2, unsigned short* __restrict__ W2t) {
  __shared__ float t[32][33];
  int d0 = blockIdx.x * 32, h0 = blockIdx.y * 32, e = blockIdx.z;
  int tx = threadIdx.x & 31, ty = threadIdx.x >> 5;
  const float* src = W2 + (size_t)e * HID * DIM;
  for (int i = 0; i < 32; i += 8)
    t[ty + i][tx] = src[(size_t)(h0 + ty + i) * DIM + d0 + tx];
  __syncthreads();
  unsigned short* dst = W2t + (size_t)e * DIM * HID;
  for (int i = 0; i < 32; i += 8)
    dst[(size_t)(d0 + ty + i) * HID + h0 + tx] = f2bf(t[tx][ty + i]);
}

// ---------------- b1 [E][2H] -> packed b1p [E][2H] (pairs a,g) ----------------
__global__ void k_pack_b1(const float* __restrict__ b1, float* __restrict__ b1p) {
  int g = blockIdx.x * blockDim.x + threadIdx.x;
  int e = g >> 13, r = g & (TWO_H - 1);
  int h = r >> 1, p = r & 1;
  b1p[g] = b1[e * TWO_H + p * HID + h];
}

// ---------------- router v2: 16 tokens/block, block-local reduction ----------------
__global__ void __launch_bounds__(256) k_router(
    const float* __restrict__ x, const float* __restrict__ Wr, const float* __restrict__ br,
    int* __restrict__ idx, float* __restrict__ gate,
    float* __restrict__ imp, float* __restrict__ zsum) {
  __shared__ float sW[TWO_H];          // 32 KB  (Wr is [D][E] = 1024*8)
  __shared__ float sX[16 * 1028];      // 65.8 KB
  __shared__ float sLG[16 * 8];
  __shared__ float sImp[8];
  __shared__ float sZ;
  int tid = threadIdx.x;
  if (tid < 8) sImp[tid] = 0.f;
  if (tid == 8) sZ = 0.f;
  for (int i = 0; i < 8; ++i) {
    int g = tid + i * 256;
    *(float4*)&sW[g * 4] = *(const float4*)&Wr[g * 4];
  }
  int t0 = blockIdx.x * 16;
  const float* xb = x + (size_t)t0 * DIM;
  for (int i = 0; i < 16; ++i) {
    int g = tid + i * 256;           // global float4 index within 16 rows
    int row = g >> 8, c = (g & 255) * 4;
    *(float4*)&sX[row * 1028 + c] = *(const float4*)&xb[(size_t)g * 4];
  }
  __syncthreads();
  int t = tid >> 4, e = (tid >> 1) & 7, half = tid & 1;
  const float* xr = &sX[t * 1028 + half * 512];
  float s = 0.f;
  for (int k = 0; k < 512; k += 4) {
    float4 xv = *(const float4*)&xr[k];
    int kb = (half * 512 + k) * 8 + e;
    s += xv.x * sW[kb] + xv.y * sW[kb + 8] + xv.z * sW[kb + 16] + xv.w * sW[kb + 24];
  }
  s += __shfl_xor(s, 1);               // combine the two K-halves
  if (half == 0) sLG[t * 8 + e] = s + br[e];
  __syncthreads();
  if (tid < 16) {
    int n = t0 + tid;
    float lg[8];
    for (int i = 0; i < 8; ++i) lg[i] = sLG[tid * 8 + i];
    float mx = lg[0];
    for (int i = 1; i < 8; ++i) mx = fmaxf(mx, lg[i]);
    float ex[8], den = 0.f, zs = 0.f;
    for (int i = 0; i < 8; ++i) { ex[i] = __expf(lg[i] - mx); den += ex[i]; zs += lg[i] * lg[i]; }
    atomicAdd(&sZ, zs);
    float rden = 1.f / den;
    for (int i = 0; i < 8; ++i) atomicAdd(&sImp[i], ex[i] * rden);
    int i1 = 0;
    for (int i = 1; i < 8; ++i) if (lg[i] > lg[i1]) i1 = i;     // ties -> lowest idx, like top_k
    int i2 = -1;
    for (int i = 0; i < 8; ++i) { if (i == i1) continue; if (i2 < 0 || lg[i] > lg[i2]) i2 = i; }
    float e2 = __expf(lg[i2] - lg[i1]);
    float g1 = 1.f / (1.f + e2);
    idx[n * 2] = i1; idx[n * 2 + 1] = i2;
    gate[n * 2] = g1; gate[n * 2 + 1] = 1.f - g1;
  }
  __syncthreads();
  if (tid < 8) atomicAdd(&imp[tid], sImp[tid]);
  if (tid == 8) atomicAdd(zsum, sZ);
}

// ---------------- per-expert sequential position scan (flat order s = k*N + n) -----
__global__ void k_scan(const int* __restrict__ idx, int* __restrict__ pos, int* __restrict__ cnt) {
  int wave = threadIdx.x >> 6, lane = threadIdx.x & 63;  // wave == expert id
  int base = 0;
  for (int c = 0; c < (2 * N_TOK) / 64; ++c) {
    int s = c * 64 + lane;
    int n = s & (N_TOK - 1), k = s >> 12;
    int e = idx[n * 2 + k];
    unsigned long long m = __ballot(e == wave);
    if (e == wave) pos[s] = base + __popcll(m & ((1ull << lane) - 1ull));
    base += __popcll(m);
  }
  if (lane == 0) cnt[wave] = base;
}

// ---------------- renormalized kept gates ----------------
__global__ void k_weights(const float* __restrict__ gate, const int* __restrict__ pos,
                          float* __restrict__ wn) {
  int n = blockIdx.x * blockDim.x + threadIdx.x;
  if (n >= N_TOK) return;
  float g0 = gate[n * 2], g1 = gate[n * 2 + 1];
  float k0 = (pos[n] < CAP) ? g0 : 0.f;
  float k1 = (pos[N_TOK + n] < CAP) ? g1 : 0.f;
  float den = fmaxf(k0 + k1, 1e-8f);
  wn[n * 2] = k0 / den; wn[n * 2 + 1] = k1 / den;
}

// ---------------- gather + per-expert LayerNorm -> Xn bf16 [E][CAP][D] ----------------
__global__ void __launch_bounds__(256) k_gather_ln(
    const float* __restrict__ x, const float* __restrict__ lns, const float* __restrict__ lnb,
    const int* __restrict__ idx, const int* __restrict__ pos, unsigned short* __restrict__ Xn) {
  int s = blockIdx.x;
  int p = pos[s];
  if (p >= CAP) return;                       // dropped slot (block-uniform exit)
  int n = s & (N_TOK - 1), k = s >> 12;
  int e = idx[n * 2 + k];
  const float* xr = x + (size_t)n * DIM;
  int tid = threadIdx.x;
  float v[4], sum = 0.f, sq = 0.f;
  for (int i = 0; i < 4; ++i) { v[i] = xr[tid + i * 256]; sum += v[i]; sq += v[i] * v[i]; }
  for (int o = 32; o > 0; o >>= 1) { sum += __shfl_down(sum, o); sq += __shfl_down(sq, o); }
  __shared__ float ws[8];
  int wv = tid >> 6, ln = tid & 63;
  if (ln == 0) { ws[wv] = sum; ws[4 + wv] = sq; }
  __syncthreads();
  sum = ws[0] + ws[1] + ws[2] + ws[3];
  sq  = ws[4] + ws[5] + ws[6] + ws[7];
  float mu = sum * (1.f / DIM);
  float var = sq * (1.f / DIM) - mu * mu;
  float rs = rsqrtf(var + 1e-5f);
  unsigned short* orow = Xn + ((size_t)e * CAP + p) * DIM;
  const float* sc = lns + (size_t)e * DIM;
  const float* bi = lnb + (size_t)e * DIM;
  for (int i = 0; i < 4; ++i) {
    int d = tid + i * 256;
    orow[d] = f2bf((v[i] - mu) * rs * sc[d] + bi[d]);
  }
}

// ---------------- bf16 MFMA GEMM: C[m][n] = sum_k A[m][k] * B[n][k]  (B is N-major, B^T) ----
// R3: global_load_lds (linear dest is HW-mandatory) + T2-equivalent XOR swizzle done
// BOTH-sides-or-neither (rule #21): pre-swizzle the per-lane GLOBAL source chunk
// (chunk' = (l&7)^(l>>3)) so LDS[r][j] = G[r][j ^ (r&7)]; fragment reads apply the
// same XOR (col ^ ((row&7)<<3)). R2 measured the linear layout's 16-way ds_read
// conflict: SQ_LDS_BANK_CONFLICT 6.6e7, MfmaUtil 19%. After swizzle each quad-group's
// 16 lanes hit 8 distinct 16B slots (2-way = free, m136). Both XORs are lane-constant
// -> folded into base addrs, zero per-iteration cost. Coalescing preserved (chunk
// permutation stays within each 128B row).
// T1 bijective XCD swizzle kept (R2: FETCH 620 -> 124 MB, verified).
template<bool GLU>
__global__ void __launch_bounds__(256) k_gemm(
    const unsigned short* __restrict__ A,   // [E][M][K]
    const unsigned short* __restrict__ B,   // [E][Nn][K]
    const float* __restrict__ bias,         // b1p [E][2H] (only used if GLU)
    unsigned short* __restrict__ Cout,      // GLU: [E][M][Nn/2] else [E][M][Nn]
    int M, int Nn, int K) {
  // sA/sB: 2 x 128x64 shorts = 32 KB; epilogue staging needs up to 128*136 shorts
  __shared__ __align__(16) unsigned short smem[17408];   // 34.8 KB
  unsigned short* sA = smem;              // [128][64], content XOR-swizzled per row
  unsigned short* sB = smem + 128 * 64;

  // T1 XCD swizzle: physical bid -> logical lid; contiguous lid chunk per XCD
  int gx = gridDim.x, gy = gridDim.y;
  int nwg = gx * gy * (int)gridDim.z;
  int bid = blockIdx.x + gx * (blockIdx.y + gy * blockIdx.z);
  int lid = (bid & 7) * (nwg >> 3) + (bid >> 3);
  int bm = lid % gx; int rest = lid / gx;
  int e  = rest / gy;
  int m0 = bm * 128, n0 = (rest % gy) * 128;

  const unsigned short* Ae = A + (size_t)e * M * K;
  const unsigned short* Be = B + (size_t)e * Nn * K;
  int tid = threadIdx.x;
  int lane = tid & 63, wave = tid >> 6;
  int wm = (wave >> 1) * 64, wn = (wave & 1) * 64;
  int quad = lane >> 4, l16 = lane & 15;
  f32x4 acc[4][4];
  for (int i = 0; i < 4; ++i)
    for (int j = 0; j < 4; ++j) acc[i][j] = f32x4{0.f, 0.f, 0.f, 0.f};

  // staging geometry: wave w owns rows [w*32, w*32+32); per gll16 call one wave DMAs
  // 8 rows x 128B (lane l -> LDS row c*8 + (l>>3), chunk l&7).
  // PRE-SWIZZLED global source: chunk' = (l&7) ^ (l>>3)  (r&7 == l>>3 for all calls)
  int srr = lane >> 3;                        // row within 8-row group
  int scc = (lane & 7) ^ srr;                 // swizzled 16B chunk within row
  const unsigned short* Ag = Ae + (size_t)(m0 + wave * 32 + srr) * K + scc * 8;
  const unsigned short* Bg = Be + (size_t)(n0 + wave * 32 + srr) * K + scc * 8;
  unsigned short* sAw = sA + wave * (32 * 64);
  unsigned short* sBw = sB + wave * (32 * 64);

  // fragment-read swizzle: (row&7) == (l16&7) since wm, wn, i*16 are multiples of 8
  int swz = (l16 & 7) << 3;

  for (int k0 = 0; k0 < K; k0 += 64) {
    __syncthreads();                       // prev compute done before overwrite
    for (int c = 0; c < 4; ++c) {
      gll16(Ag + (size_t)(c * 8) * K + k0, sAw + c * (8 * 64));
      gll16(Bg + (size_t)(c * 8) * K + k0, sBw + c * (8 * 64));
    }
    __syncthreads();                       // compiler drains vmcnt(0) before barrier
    for (int kk = 0; kk < 64; kk += 32) {
      bf16x8 aF[4], bF[4];
      int col = (kk + quad * 8) ^ swz;
      for (int i = 0; i < 4; ++i) {
        aF[i] = *(const bf16x8*)&sA[(wm + i * 16 + l16) * 64 + col];
        bF[i] = *(const bf16x8*)&sB[(wn + i * 16 + l16) * 64 + col];
      }
      for (int i = 0; i < 4; ++i)
        for (int j = 0; j < 4; ++j)
          acc[i][j] = __builtin_amdgcn_mfma_f32_16x16x32_bf16(aF[i], bF[j], acc[i][j], 0, 0, 0);
    }
  }
  __syncthreads();   // K-loop LDS reads done in all waves; smem is reused below
  if (GLU) {
    const float* bp = bias + (size_t)e * TWO_H;
    unsigned short* Ce = Cout + (size_t)e * M * (Nn >> 1);
    // stage packed GLU output tile: [128 rows][64 shorts], row stride 80 (160B, 16B-mult)
    for (int i = 0; i < 4; ++i)
      for (int j = 0; j < 4; ++j) {
        int pn = n0 + wn + j * 16 + l16;
        float b = bp[pn];
        for (int r = 0; r < 4; ++r) {
          int row = wm + i * 16 + quad * 4 + r;
          float u = acc[i][j][r] + b;          // includes bias for both a and g lanes
          float g = __shfl_xor(u, 1);          // partner column (pn^1)
          if ((l16 & 1) == 0) {                // even col = a, partner = g
            float vv = u / (1.f + __expf(-g));
            smem[row * 80 + ((wn + j * 16 + l16) >> 1)] = f2bf(vv);
          }
        }
      }
    __syncthreads();
    // cooperative coalesced store: 64 shorts (128B) per row, 8 lanes x int4
    int c = tid & 7, row0 = tid >> 3;
    for (int p = 0; p < 4; ++p) {
      int row = row0 + p * 32;
      *(int4*)&Ce[(size_t)(m0 + row) * (Nn >> 1) + (n0 >> 1) + c * 8] =
          *(const int4*)&smem[row * 80 + c * 8];
    }
  } else {
    unsigned short* Ce = Cout + (size_t)e * M * Nn;
    // stage output tile: [128 rows][128 shorts], row stride 136 (272B, 16B-mult)
    for (int i = 0; i < 4; ++i)
      for (int j = 0; j < 4; ++j) {
        int col = wn + j * 16 + l16;
        for (int r = 0; r < 4; ++r) {
          int row = wm + i * 16 + quad * 4 + r;
          smem[row * 136 + col] = f2bf(acc[i][j][r]);
        }
      }
    __syncthreads();
    // cooperative coalesced store: 128 shorts (256B) per row, 16 lanes x int4
    int c = tid & 15, row0 = tid >> 4;
    for (int p = 0; p < 8; ++p) {
      int row = row0 + p * 16;
      *(int4*)&Ce[(size_t)(m0 + row) * Nn + n0 + c * 8] =
          *(const int4*)&smem[row * 136 + c * 8];
    }
  }
}

// ---------------- combine: y[n] = sum_k w_k * (Yexp[e_k][p_k] + b2[e_k]) ----------------
__global__ void __launch_bounds__(256) k_gather_out(
    const unsigned short* __restrict__ Yexp, const float* __restrict__ b2,
    const int* __restrict__ idx, const int* __restrict__ pos,
    const float* __restrict__ wn, float* __restrict__ y) {
  int n = blockIdx.x, tid = threadIdx.x;
  int e0 = idx[n * 2], e1 = idx[n * 2 + 1];
  int p0 = min(pos[n], CAP - 1), p1 = min(pos[N_TOK + n], CAP - 1);
  float w0 = wn[n * 2], w1 = wn[n * 2 + 1];
  const unsigned short* r0 = Yexp + ((size_t)e0 * CAP + p0) * DIM;
  const unsigned short* r1 = Yexp + ((size_t)e1 * CAP + p1) * DIM;
  const float* bb0 = b2 + (size_t)e0 * DIM;
  const float* bb1 = b2 + (size_t)e1 * DIM;
  float* yr = y + (size_t)n * DIM;
  for (int i = 0; i < 4; ++i) {
    int d = tid + i * 256;
    yr[d] = w0 * (bf2f(r0[d]) + bb0[d]) + w1 * (bf2f(r1[d]) + bb1[d]);
  }
}

// ---------------- scalar losses ----------------
__global__ void k_losses(const float* __restrict__ imp, const int* __restrict__ cnt,
                         const float* __restrict__ zsum, float* __restrict__ out) {
  if (threadIdx.x != 0 || blockIdx.x != 0) return;
  double li[8], ll[8], mi = 0.0, ml = 0.0;
  for (int i = 0; i < 8; ++i) {
    li[i] = imp[i];
    ll[i] = (double)min(cnt[i], CAP);
    mi += li[i]; ml += ll[i];
  }
  mi /= 8.0; ml /= 8.0;
  double vi = 0.0, vl = 0.0;
  for (int i = 0; i < 8; ++i) { vi += (li[i] - mi) * (li[i] - mi); vl += (ll[i] - ml) * (ll[i] - ml); }
  vi /= 8.0; vl /= 8.0;
  const double eps = 1e-9;
  double cvi = vi / (fmax(mi, eps) * fmax(mi, eps) + eps);
  double cvl = vl / (fmax(ml, eps) * fmax(ml, eps) + eps);
  out[0] = (float)(0.5 * (cvi + cvl));
  out[1] = (float)((double)zsum[0] / (double)(N_TOK * NEXP) * 1e-4);
}

extern "C" void kernel_launch(void* const* d_in, const int* in_sizes, int n_in,
                              void* d_out, int out_size, void* d_ws, size_t ws_size,
                              hipStream_t stream) {
  const float* h   = (const float*)d_in[0];
  const float* Wr  = (const float*)d_in[1];
  const float* br  = (const float*)d_in[2];
  const float* lns = (const float*)d_in[3];
  const float* lnb = (const float*)d_in[4];
  const float* W1  = (const float*)d_in[5];
  const float* b1  = (const float*)d_in[6];
  const float* W2  = (const float*)d_in[7];
  const float* b2  = (const float*)d_in[8];
  float* out = (float*)d_out;

  char* ws = (char*)d_ws;
  size_t off = 0;
  auto alloc = [&](size_t bytes) { char* p = ws + off; off += (bytes + 255) & ~(size_t)255; return p; };
  unsigned short* W1t = (unsigned short*)alloc((size_t)NEXP * TWO_H * DIM * 2);  // 134 MB
  unsigned short* W2t = (unsigned short*)alloc((size_t)NEXP * DIM * HID * 2);    // 67 MB
  unsigned short* Xn  = (unsigned short*)alloc((size_t)NEXP * CAP * DIM * 2);    // 21 MB
  unsigned short* V   = (unsigned short*)alloc((size_t)NEXP * CAP * HID * 2);    // 84 MB
  unsigned short* Yx  = (unsigned short*)alloc((size_t)NEXP * CAP * DIM * 2);    // 21 MB
  float* b1p  = (float*)alloc((size_t)NEXP * TWO_H * 4);
  int*   idx  = (int*)alloc((size_t)N_TOK * 2 * 4);
  float* gate = (float*)alloc((size_t)N_TOK * 2 * 4);
  float* wn   = (float*)alloc((size_t)N_TOK * 2 * 4);
  int*   pos  = (int*)alloc((size_t)2 * N_TOK * 4);
  int*   cnt  = (int*)alloc(64);
  float* imp  = (float*)alloc(64);
  float* zsum = (float*)alloc(64);
  (void)ws_size; (void)in_sizes; (void)n_in; (void)out_size;

  k_zero<<<dim3(1), dim3(64), 0, stream>>>(imp, zsum);
  k_conv_w1<<<dim3(HID / 32, DIM / 32, NEXP), dim3(256), 0, stream>>>(W1, W1t);
  k_conv_w2<<<dim3(DIM / 32, HID / 32, NEXP), dim3(256), 0, stream>>>(W2, W2t);
  k_pack_b1<<<dim3(NEXP * TWO_H / 256), dim3(256), 0, stream>>>(b1, b1p);
  k_router<<<dim3(N_TOK / 16), dim3(256), 0, stream>>>(h, Wr, br, idx, gate, imp, zsum);
  k_scan<<<dim3(1), dim3(512), 0, stream>>>(idx, pos, cnt);
  k_weights<<<dim3(16), dim3(256), 0, stream>>>(gate, pos, wn);
  k_gather_ln<<<dim3(2 * N_TOK), dim3(256), 0, stream>>>(h, lns, lnb, idx, pos, Xn);
  k_gemm<true><<<dim3(CAP / 128, TWO_H / 128, NEXP), dim3(256), 0, stream>>>(
      Xn, W1t, b1p, V, CAP, TWO_H, DIM);
  k_gemm<false><<<dim3(CAP / 128, DIM / 128, NEXP), dim3(256), 0, stream>>>(
      V, W2t, b1p, Yx, CAP, DIM, HID);
  k_gather_out<<<dim3(N_TOK), dim3(256), 0, stream>>>(Yx, b2, idx, pos, wn, out);
  k_losses<<<dim3(1), dim3(64), 0, stream>>>(imp, cnt, zsum, out + (size_t)N_TOK * DIM);
}

// Round 4
// 889.309 us; speedup vs baseline: 1.2550x; 1.0444x over previous
//
#include <hip/hip_runtime.h>
#include <cstdint>
#include <cstddef>

#define N_TOK 4096
#define DIM   1024
#define NEXP  8
#define HID   4096
#define TWO_H 8192
#define CAP   1280

typedef __bf16 bf16x8 __attribute__((ext_vector_type(8)));
typedef float  f32x4  __attribute__((ext_vector_type(4)));

__device__ __forceinline__ unsigned short f2bf(float f) {
  union { float f; unsigned u; } v; v.f = f;
  unsigned r = v.u + 0x7FFF + ((v.u >> 16) & 1);   // RNE
  return (unsigned short)(r >> 16);
}
__device__ __forceinline__ float bf2f(unsigned short b) {
  union { unsigned u; float f; } v; v.u = ((unsigned)b) << 16;
  return v.f;
}

// async global->LDS DMA, 16B per lane; LDS dest = wave-uniform base + lane*16
__device__ __forceinline__ void gll16(const unsigned short* g, unsigned short* l) {
  __builtin_amdgcn_global_load_lds(
      (const __attribute__((address_space(1))) uint32_t*)g,
      (__attribute__((address_space(3))) uint32_t*)l, 16, 0, 0);
}

// ---------------- zero accumulators ----------------
__global__ void k_zero(float* imp, float* zsum) {
  if (threadIdx.x < NEXP) imp[threadIdx.x] = 0.f;
  if (threadIdx.x == 0) zsum[0] = 0.f;
}

// ---------------- W1 [E][D][2H] fp32 -> packed W1t [E][2H][D] bf16 ----------------
__global__ void k_conv_w1(const float* __restrict__ W1, unsigned short* __restrict__ W1t) {
  __shared__ float tA[32][33];
  __shared__ float tG[32][33];
  int h0 = blockIdx.x * 32, d0 = blockIdx.y * 32, e = blockIdx.z;
  int tx = threadIdx.x & 31, ty = threadIdx.x >> 5;  // ty 0..7
  const float* src = W1 + (size_t)e * DIM * TWO_H;
  for (int i = 0; i < 32; i += 8) {
    int d = d0 + ty + i;
    tA[ty + i][tx] = src[(size_t)d * TWO_H + h0 + tx];
    tG[ty + i][tx] = src[(size_t)d * TWO_H + HID + h0 + tx];
  }
  __syncthreads();
  unsigned short* dst = W1t + (size_t)e * TWO_H * DIM;
  for (int i = 0; i < 64; i += 8) {
    int r = ty + i;                  // 0..63 local packed row
    int hh = r >> 1, p = r & 1;
    float v = p ? tG[tx][hh] : tA[tx][hh];
    dst[(size_t)(2 * h0 + r) * DIM + d0 + tx] = f2bf(v);
  }
}

// ---------------- W2 [E][H][D] fp32 -> W2t [E][D][H] bf16 ----------------
__global__ void k_conv_w2(const float* __restrict__ W2, unsigned short* __restrict__ W2t) {
  __shared__ float t[32][33];
  int d0 = blockIdx.x * 32, h0 = blockIdx.y * 32, e = blockIdx.z;
  int tx = threadIdx.x & 31, ty = threadIdx.x >> 5;
  const float* src = W2 + (size_t)e * HID * DIM;
  for (int i = 0; i < 32; i += 8)
    t[ty + i][tx] = src[(size_t)(h0 + ty + i) * DIM + d0 + tx];
  __syncthreads();
  unsigned short* dst = W2t + (size_t)e * DIM * HID;
  for (int i = 0; i < 32; i += 8)
    dst[(size_t)(d0 + ty + i) * HID + h0 + tx] = f2bf(t[tx][ty + i]);
}

// ---------------- b1 [E][2H] -> packed b1p [E][2H] (pairs a,g) ----------------
__global__ void k_pack_b1(const float* __restrict__ b1, float* __restrict__ b1p) {
  int g = blockIdx.x * blockDim.x + threadIdx.x;
  int e = g >> 13, r = g & (TWO_H - 1);
  int h = r >> 1, p = r & 1;
  b1p[g] = b1[e * TWO_H + p * HID + h];
}

// ---------------- router v2: 16 tokens/block, block-local reduction ----------------
__global__ void __launch_bounds__(256) k_router(
    const float* __restrict__ x, const float* __restrict__ Wr, const float* __restrict__ br,
    int* __restrict__ idx, float* __restrict__ gate,
    float* __restrict__ imp, float* __restrict__ zsum) {
  __shared__ float sW[TWO_H];          // 32 KB  (Wr is [D][E] = 1024*8)
  __shared__ float sX[16 * 1028];      // 65.8 KB
  __shared__ float sLG[16 * 8];
  __shared__ float sImp[8];
  __shared__ float sZ;
  int tid = threadIdx.x;
  if (tid < 8) sImp[tid] = 0.f;
  if (tid == 8) sZ = 0.f;
  for (int i = 0; i < 8; ++i) {
    int g = tid + i * 256;
    *(float4*)&sW[g * 4] = *(const float4*)&Wr[g * 4];
  }
  int t0 = blockIdx.x * 16;
  const float* xb = x + (size_t)t0 * DIM;
  for (int i = 0; i < 16; ++i) {
    int g = tid + i * 256;           // global float4 index within 16 rows
    int row = g >> 8, c = (g & 255) * 4;
    *(float4*)&sX[row * 1028 + c] = *(const float4*)&xb[(size_t)g * 4];
  }
  __syncthreads();
  int t = tid >> 4, e = (tid >> 1) & 7, half = tid & 1;
  const float* xr = &sX[t * 1028 + half * 512];
  float s = 0.f;
  for (int k = 0; k < 512; k += 4) {
    float4 xv = *(const float4*)&xr[k];
    int kb = (half * 512 + k) * 8 + e;
    s += xv.x * sW[kb] + xv.y * sW[kb + 8] + xv.z * sW[kb + 16] + xv.w * sW[kb + 24];
  }
  s += __shfl_xor(s, 1);               // combine the two K-halves
  if (half == 0) sLG[t * 8 + e] = s + br[e];
  __syncthreads();
  if (tid < 16) {
    int n = t0 + tid;
    float lg[8];
    for (int i = 0; i < 8; ++i) lg[i] = sLG[tid * 8 + i];
    float mx = lg[0];
    for (int i = 1; i < 8; ++i) mx = fmaxf(mx, lg[i]);
    float ex[8], den = 0.f, zs = 0.f;
    for (int i = 0; i < 8; ++i) { ex[i] = __expf(lg[i] - mx); den += ex[i]; zs += lg[i] * lg[i]; }
    atomicAdd(&sZ, zs);
    float rden = 1.f / den;
    for (int i = 0; i < 8; ++i) atomicAdd(&sImp[i], ex[i] * rden);
    int i1 = 0;
    for (int i = 1; i < 8; ++i) if (lg[i] > lg[i1]) i1 = i;     // ties -> lowest idx, like top_k
    int i2 = -1;
    for (int i = 0; i < 8; ++i) { if (i == i1) continue; if (i2 < 0 || lg[i] > lg[i2]) i2 = i; }
    float e2 = __expf(lg[i2] - lg[i1]);
    float g1 = 1.f / (1.f + e2);
    idx[n * 2] = i1; idx[n * 2 + 1] = i2;
    gate[n * 2] = g1; gate[n * 2 + 1] = 1.f - g1;
  }
  __syncthreads();
  if (tid < 8) atomicAdd(&imp[tid], sImp[tid]);
  if (tid == 8) atomicAdd(zsum, sZ);
}

// ---------------- per-expert sequential position scan (flat order s = k*N + n) -----
__global__ void k_scan(const int* __restrict__ idx, int* __restrict__ pos, int* __restrict__ cnt) {
  int wave = threadIdx.x >> 6, lane = threadIdx.x & 63;  // wave == expert id
  int base = 0;
  for (int c = 0; c < (2 * N_TOK) / 64; ++c) {
    int s = c * 64 + lane;
    int n = s & (N_TOK - 1), k = s >> 12;
    int e = idx[n * 2 + k];
    unsigned long long m = __ballot(e == wave);
    if (e == wave) pos[s] = base + __popcll(m & ((1ull << lane) - 1ull));
    base += __popcll(m);
  }
  if (lane == 0) cnt[wave] = base;
}

// ---------------- renormalized kept gates ----------------
__global__ void k_weights(const float* __restrict__ gate, const int* __restrict__ pos,
                          float* __restrict__ wn) {
  int n = blockIdx.x * blockDim.x + threadIdx.x;
  if (n >= N_TOK) return;
  float g0 = gate[n * 2], g1 = gate[n * 2 + 1];
  float k0 = (pos[n] < CAP) ? g0 : 0.f;
  float k1 = (pos[N_TOK + n] < CAP) ? g1 : 0.f;
  float den = fmaxf(k0 + k1, 1e-8f);
  wn[n * 2] = k0 / den; wn[n * 2 + 1] = k1 / den;
}

// ---------------- gather + per-expert LayerNorm -> Xn bf16 [E][CAP][D] ----------------
__global__ void __launch_bounds__(256) k_gather_ln(
    const float* __restrict__ x, const float* __restrict__ lns, const float* __restrict__ lnb,
    const int* __restrict__ idx, const int* __restrict__ pos, unsigned short* __restrict__ Xn) {
  int s = blockIdx.x;
  int p = pos[s];
  if (p >= CAP) return;                       // dropped slot (block-uniform exit)
  int n = s & (N_TOK - 1), k = s >> 12;
  int e = idx[n * 2 + k];
  const float* xr = x + (size_t)n * DIM;
  int tid = threadIdx.x;
  float v[4], sum = 0.f, sq = 0.f;
  for (int i = 0; i < 4; ++i) { v[i] = xr[tid + i * 256]; sum += v[i]; sq += v[i] * v[i]; }
  for (int o = 32; o > 0; o >>= 1) { sum += __shfl_down(sum, o); sq += __shfl_down(sq, o); }
  __shared__ float ws[8];
  int wv = tid >> 6, ln = tid & 63;
  if (ln == 0) { ws[wv] = sum; ws[4 + wv] = sq; }
  __syncthreads();
  sum = ws[0] + ws[1] + ws[2] + ws[3];
  sq  = ws[4] + ws[5] + ws[6] + ws[7];
  float mu = sum * (1.f / DIM);
  float var = sq * (1.f / DIM) - mu * mu;
  float rs = rsqrtf(var + 1e-5f);
  unsigned short* orow = Xn + ((size_t)e * CAP + p) * DIM;
  const float* sc = lns + (size_t)e * DIM;
  const float* bi = lnb + (size_t)e * DIM;
  for (int i = 0; i < 4; ++i) {
    int d = tid + i * 256;
    orow[d] = f2bf((v[i] - mu) * rs * sc[d] + bi[d]);
  }
}

// ---------------- bf16 MFMA GEMM, 256x256 tile, 8-phase counted-vmcnt schedule ----
// R4: full T2+T3+T4+T5 port (guide §5 template, m201). 8 waves (2Mx4N), BK=64.
// LDS = ring of 8 K-half slots (2-Ktile dbuf x 2 K-halves x {A,B}), slot = 256rows x
// 32cols bf16 (16KB, 64B rows). Per K-tile 4 phases: {ds_read frags || stage 1
// half-tile (2 gll16) -> s_barrier -> lgkmcnt(0) -> setprio(1)+16 MFMA -> s_barrier}.
// Counted vmcnt(4) (=2 half-tiles in flight) at phases 2 & 4 only — never 0 in loop.
// Stage queue (steady): p1->A(t+1,kh1) p2->B(t+1,kh1) p3->A(t+2,kh0) p4->B(t+2,kh0);
// every staged half has vmcnt-rank >=5 at its guarding wait, and every slot write is
// issued only after the previous reader phase's lgkmcnt(0)+barrier (race-checked).
// Swizzle (both-sides, rule #21): 64B rows -> read chunk quad^((l16>>1)&3), matching
// gll16 source chunk (tid&3)^((tid>>3)&3): structural-min bank use (2 lanes/bank).
// T1 bijective XCD swizzle kept (R2: FETCH 620->124 MB).
template<bool GLU, int M_, int N_, int K_>
__global__ void __launch_bounds__(512, 2) k_gemm(
    const unsigned short* __restrict__ A,   // [E][M_][K_]
    const unsigned short* __restrict__ B,   // [E][N_][K_]  (B^T, N-major)
    const float* __restrict__ bias,         // b1p [E][2H] (GLU only)
    unsigned short* __restrict__ Cout) {    // GLU: [E][M_][N_/2] else [E][M_][N_]
  constexpr int KT = K_ / 64;
  __shared__ __align__(16) unsigned short smem[65536];   // 128 KB

  constexpr int gx = M_ / 256, gy = N_ / 256;
  constexpr int nwg = gx * gy * NEXP;
  int bid = blockIdx.x + gx * (blockIdx.y + gy * blockIdx.z);
  int lid = (bid & 7) * (nwg >> 3) + (bid >> 3);
  int bm = lid % gx; int rest = lid / gx;
  int e  = rest / gy;
  int m0 = bm * 256, n0 = (rest % gy) * 256;

  const unsigned short* Ae = A + (size_t)e * M_ * K_;
  const unsigned short* Be = B + (size_t)e * N_ * K_;
  int tid = threadIdx.x, lane = tid & 63, wave = tid >> 6;
  int wm = wave >> 2, wn = wave & 3;           // 2 x 4 wave grid
  int quad = lane >> 4, l16 = lane & 15;

  f32x4 acc[8][4];
#pragma unroll
  for (int i = 0; i < 8; ++i)
#pragma unroll
    for (int j = 0; j < 4; ++j) acc[i][j] = f32x4{0.f, 0.f, 0.f, 0.f};

  // ---- staging setup: half-tile = 256 rows x 32 cols; 2 gll16 calls (c=0:rows0-127) -
  int ch = (tid & 3) ^ ((tid >> 3) & 3);       // pre-swizzled source chunk
  const unsigned short* Ag0 = Ae + (size_t)(m0 + (tid >> 2)) * K_ + ch * 8;
  const unsigned short* Bg0 = Be + (size_t)(n0 + (tid >> 2)) * K_ + ch * 8;
  unsigned short* sw = smem + wave * 512;      // wave-uniform LDS dest base (shorts)

#define STG(gp, bofs, ks, kh) do {                                   \
    int q_ = (2 * (ks) + (kh)) & 3;                                  \
    int kc_ = (ks) < KT ? (ks) : KT - 1;                             \
    size_t ko_ = (size_t)(kc_ * 64 + (kh) * 32);                     \
    gll16(gp + ko_, sw + (bofs) + q_ * 8192);                        \
    gll16(gp + (size_t)128 * K_ + ko_, sw + (bofs) + q_ * 8192 + 4096); \
  } while (0)

  // ---- fragment-read setup (swizzled; (row>>1)&3 == (l16>>1)&3 for all frags) ----
  int chR = quad ^ ((l16 >> 1) & 3);
  const unsigned short* rdA = smem + (wm * 128 + l16) * 32 + chR * 8;
  const unsigned short* rdB = smem + 32768 + (wn * 64 + l16) * 32 + chR * 8;

  bf16x8 aF[4], bF[4];
#define LDB(q) { _Pragma("unroll") for (int nf = 0; nf < 4; ++nf) \
    bF[nf] = *(const bf16x8*)(rdB + (q) * 8192 + nf * 512); }
#define LDA(q, h) { _Pragma("unroll") for (int mf = 0; mf < 4; ++mf) \
    aF[mf] = *(const bf16x8*)(rdA + (q) * 8192 + ((h) * 4 + mf) * 512); }
#define MM(h) { _Pragma("unroll") for (int mf = 0; mf < 4; ++mf) \
    _Pragma("unroll") for (int nf = 0; nf < 4; ++nf) \
    acc[(h)*4+mf][nf] = __builtin_amdgcn_mfma_f32_16x16x32_bf16(aF[mf], bF[nf], acc[(h)*4+mf][nf], 0, 0, 0); }
#define WAIT_LGKM0 { asm volatile("s_waitcnt lgkmcnt(0)" ::: "memory"); __builtin_amdgcn_sched_barrier(0); }
#define WAIT_VM4   { asm volatile("s_waitcnt vmcnt(4)"   ::: "memory"); __builtin_amdgcn_sched_barrier(0); }

  // ---- prologue: stage (0,kh0)(0,kh1)(1,kh0); wait oldest 4 loads = (0,kh0) ----
  STG(Ag0, 0, 0, 0); STG(Bg0, 32768, 0, 0);
  STG(Ag0, 0, 0, 1); STG(Bg0, 32768, 0, 1);
  STG(Ag0, 0, 1, 0); STG(Bg0, 32768, 1, 0);
  asm volatile("s_waitcnt vmcnt(8)" ::: "memory");
  __builtin_amdgcn_sched_barrier(0);
  __builtin_amdgcn_s_barrier();

  for (int kt = 0; kt < KT; ++kt) {
    int q0 = (2 * kt) & 3, q1 = (2 * kt + 1) & 3;
    // ---- phase 1: kh0 x m0-3 ----
    LDB(q0); LDA(q0, 0);
    STG(Ag0, 0, kt + 1, 1);
    __builtin_amdgcn_s_barrier();
    WAIT_LGKM0;
    __builtin_amdgcn_s_setprio(1); MM(0); __builtin_amdgcn_s_setprio(0);
    __builtin_amdgcn_s_barrier();
    // ---- phase 2: kh0 x m4-7 (B reused) ----
    LDA(q0, 1);
    STG(Bg0, 32768, kt + 1, 1);
    WAIT_VM4;                        // guards (kt,kh1) for phase 3
    __builtin_amdgcn_s_barrier();
    WAIT_LGKM0;
    __builtin_amdgcn_s_setprio(1); MM(1); __builtin_amdgcn_s_setprio(0);
    __builtin_amdgcn_s_barrier();
    // ---- phase 3: kh1 x m0-3 ----
    LDB(q1); LDA(q1, 0);
    STG(Ag0, 0, kt + 2, 0);
    __builtin_amdgcn_s_barrier();
    WAIT_LGKM0;
    __builtin_amdgcn_s_setprio(1); MM(0); __builtin_amdgcn_s_setprio(0);
    __builtin_amdgcn_s_barrier();
    // ---- phase 4: kh1 x m4-7 ----
    LDA(q1, 1);
    STG(Bg0, 32768, kt + 2, 0);
    WAIT_VM4;                        // guards (kt+1,kh0) for next p1
    __builtin_amdgcn_s_barrier();
    WAIT_LGKM0;
    __builtin_amdgcn_s_setprio(1); MM(1); __builtin_amdgcn_s_setprio(0);
    __builtin_amdgcn_s_barrier();
  }
  asm volatile("s_waitcnt vmcnt(0)" ::: "memory");
  __builtin_amdgcn_sched_barrier(0);
  __builtin_amdgcn_s_barrier();      // LDS free for epilogue reuse

  if (GLU) {
    const float* bp = bias + (size_t)e * TWO_H;
    unsigned short* Ce = Cout + (size_t)e * M_ * (N_ >> 1);
    // stage packed GLU tile: 256 rows x 128 shorts, stride 136 (16B-mult)
#pragma unroll
    for (int mf = 0; mf < 8; ++mf)
#pragma unroll
      for (int nf = 0; nf < 4; ++nf) {
        int pn = n0 + wn * 64 + nf * 16 + l16;
        float b = bp[pn];
#pragma unroll
        for (int r = 0; r < 4; ++r) {
          int row = wm * 128 + mf * 16 + quad * 4 + r;
          float u = acc[mf][nf][r] + b;
          float g = __shfl_xor(u, 1);          // partner column (pn^1)
          if ((l16 & 1) == 0) {                // even col = a, partner = g
            float vv = u / (1.f + __expf(-g));
            smem[row * 136 + ((wn * 64 + nf * 16 + l16) >> 1)] = f2bf(vv);
          }
        }
      }
    __syncthreads();
    int c = tid & 15, row0 = tid >> 4;         // 0..31
    for (int p = 0; p < 8; ++p) {
      int row = row0 + p * 32;
      *(int4*)&Ce[(size_t)(m0 + row) * (N_ >> 1) + (n0 >> 1) + c * 8] =
          *(const int4*)&smem[row * 136 + c * 8];
    }
  } else {
    unsigned short* Ce = Cout + (size_t)e * M_ * N_;
    // two passes of 128 rows (256x256 shorts won't fit LDS at once)
    for (int h = 0; h < 2; ++h) {
      if (h) __syncthreads();
#pragma unroll
      for (int mf2 = 0; mf2 < 4; ++mf2)
#pragma unroll
        for (int nf = 0; nf < 4; ++nf) {
          int mf = 4 * h + mf2;
          int col = wn * 64 + nf * 16 + l16;
          int lr = wm * 64 + mf2 * 16 + quad * 4;
#pragma unroll
          for (int r = 0; r < 4; ++r)
            smem[(lr + r) * 264 + col] = f2bf(acc[mf][nf][r]);
        }
      __syncthreads();
      int c = tid & 31, row0 = tid >> 5;       // 0..15
      for (int p = 0; p < 8; ++p) {
        int row = row0 + p * 16;               // local 0..127
        int grow = m0 + (row >> 6) * 128 + h * 64 + (row & 63);
        *(int4*)&Ce[(size_t)grow * N_ + n0 + c * 8] =
            *(const int4*)&smem[row * 264 + c * 8];
      }
    }
  }
#undef STG
#undef LDB
#undef LDA
#undef MM
#undef WAIT_LGKM0
#undef WAIT_VM4
}

// ---------------- combine: y[n] = sum_k w_k * (Yexp[e_k][p_k] + b2[e_k]) ----------------
__global__ void __launch_bounds__(256) k_gather_out(
    const unsigned short* __restrict__ Yexp, const float* __restrict__ b2,
    const int* __restrict__ idx, const int* __restrict__ pos,
    const float* __restrict__ wn, float* __restrict__ y) {
  int n = blockIdx.x, tid = threadIdx.x;
  int e0 = idx[n * 2], e1 = idx[n * 2 + 1];
  int p0 = min(pos[n], CAP - 1), p1 = min(pos[N_TOK + n], CAP - 1);
  float w0 = wn[n * 2], w1 = wn[n * 2 + 1];
  const unsigned short* r0 = Yexp + ((size_t)e0 * CAP + p0) * DIM;
  const unsigned short* r1 = Yexp + ((size_t)e1 * CAP + p1) * DIM;
  const float* bb0 = b2 + (size_t)e0 * DIM;
  const float* bb1 = b2 + (size_t)e1 * DIM;
  float* yr = y + (size_t)n * DIM;
  for (int i = 0; i < 4; ++i) {
    int d = tid + i * 256;
    yr[d] = w0 * (bf2f(r0[d]) + bb0[d]) + w1 * (bf2f(r1[d]) + bb1[d]);
  }
}

// ---------------- scalar losses ----------------
__global__ void k_losses(const float* __restrict__ imp, const int* __restrict__ cnt,
                         const float* __restrict__ zsum, float* __restrict__ out) {
  if (threadIdx.x != 0 || blockIdx.x != 0) return;
  double li[8], ll[8], mi = 0.0, ml = 0.0;
  for (int i = 0; i < 8; ++i) {
    li[i] = imp[i];
    ll[i] = (double)min(cnt[i], CAP);
    mi += li[i]; ml += ll[i];
  }
  mi /= 8.0; ml /= 8.0;
  double vi = 0.0, vl = 0.0;
  for (int i = 0; i < 8; ++i) { vi += (li[i] - mi) * (li[i] - mi); vl += (ll[i] - ml) * (ll[i] - ml); }
  vi /= 8.0; vl /= 8.0;
  const double eps = 1e-9;
  double cvi = vi / (fmax(mi, eps) * fmax(mi, eps) + eps);
  double cvl = vl / (fmax(ml, eps) * fmax(ml, eps) + eps);
  out[0] = (float)(0.5 * (cvi + cvl));
  out[1] = (float)((double)zsum[0] / (double)(N_TOK * NEXP) * 1e-4);
}

extern "C" void kernel_launch(void* const* d_in, const int* in_sizes, int n_in,
                              void* d_out, int out_size, void* d_ws, size_t ws_size,
                              hipStream_t stream) {
  const float* h   = (const float*)d_in[0];
  const float* Wr  = (const float*)d_in[1];
  const float* br  = (const float*)d_in[2];
  const float* lns = (const float*)d_in[3];
  const float* lnb = (const float*)d_in[4];
  const float* W1  = (const float*)d_in[5];
  const float* b1  = (const float*)d_in[6];
  const float* W2  = (const float*)d_in[7];
  const float* b2  = (const float*)d_in[8];
  float* out = (float*)d_out;

  char* ws = (char*)d_ws;
  size_t off = 0;
  auto alloc = [&](size_t bytes) { char* p = ws + off; off += (bytes + 255) & ~(size_t)255; return p; };
  unsigned short* W1t = (unsigned short*)alloc((size_t)NEXP * TWO_H * DIM * 2);  // 134 MB
  unsigned short* W2t = (unsigned short*)alloc((size_t)NEXP * DIM * HID * 2);    // 67 MB
  unsigned short* Xn  = (unsigned short*)alloc((size_t)NEXP * CAP * DIM * 2);    // 21 MB
  unsigned short* V   = (unsigned short*)alloc((size_t)NEXP * CAP * HID * 2);    // 84 MB
  unsigned short* Yx  = (unsigned short*)alloc((size_t)NEXP * CAP * DIM * 2);    // 21 MB
  float* b1p  = (float*)alloc((size_t)NEXP * TWO_H * 4);
  int*   idx  = (int*)alloc((size_t)N_TOK * 2 * 4);
  float* gate = (float*)alloc((size_t)N_TOK * 2 * 4);
  float* wn   = (float*)alloc((size_t)N_TOK * 2 * 4);
  int*   pos  = (int*)alloc((size_t)2 * N_TOK * 4);
  int*   cnt  = (int*)alloc(64);
  float* imp  = (float*)alloc(64);
  float* zsum = (float*)alloc(64);
  (void)ws_size; (void)in_sizes; (void)n_in; (void)out_size;

  k_zero<<<dim3(1), dim3(64), 0, stream>>>(imp, zsum);
  k_conv_w1<<<dim3(HID / 32, DIM / 32, NEXP), dim3(256), 0, stream>>>(W1, W1t);
  k_conv_w2<<<dim3(DIM / 32, HID / 32, NEXP), dim3(256), 0, stream>>>(W2, W2t);
  k_pack_b1<<<dim3(NEXP * TWO_H / 256), dim3(256), 0, stream>>>(b1, b1p);
  k_router<<<dim3(N_TOK / 16), dim3(256), 0, stream>>>(h, Wr, br, idx, gate, imp, zsum);
  k_scan<<<dim3(1), dim3(512), 0, stream>>>(idx, pos, cnt);
  k_weights<<<dim3(16), dim3(256), 0, stream>>>(gate, pos, wn);
  k_gather_ln<<<dim3(2 * N_TOK), dim3(256), 0, stream>>>(h, lns, lnb, idx, pos, Xn);
  k_gemm<true, CAP, TWO_H, DIM><<<dim3(CAP / 256, TWO_H / 256, NEXP), dim3(512), 0, stream>>>(
      Xn, W1t, b1p, V);
  k_gemm<false, CAP, DIM, HID><<<dim3(CAP / 256, DIM / 256, NEXP), dim3(512), 0, stream>>>(
      V, W2t, b1p, Yx);
  k_gather_out<<<dim3(N_TOK), dim3(256), 0, stream>>>(Yx, b2, idx, pos, wn, out);
  k_losses<<<dim3(1), dim3(64), 0, stream>>>(imp, cnt, zsum, out + (size_t)N_TOK * DIM);
}

// Round 5
// 875.048 us; speedup vs baseline: 1.2754x; 1.0163x over previous
//
#include <hip/hip_runtime.h>
#include <cstdint>
#include <cstddef>

#define N_TOK 4096
#define DIM   1024
#define NEXP  8
#define HID   4096
#define TWO_H 8192
#define CAP   1280

typedef __bf16 bf16x8 __attribute__((ext_vector_type(8)));
typedef float  f32x4  __attribute__((ext_vector_type(4)));

__device__ __forceinline__ unsigned short f2bf(float f) {
  union { float f; unsigned u; } v; v.f = f;
  unsigned r = v.u + 0x7FFF + ((v.u >> 16) & 1);   // RNE
  return (unsigned short)(r >> 16);
}
__device__ __forceinline__ float bf2f(unsigned short b) {
  union { unsigned u; float f; } v; v.u = ((unsigned)b) << 16;
  return v.f;
}

// async global->LDS DMA, 16B per lane; LDS dest = wave-uniform base + lane*16
__device__ __forceinline__ void gll16(const unsigned short* g, unsigned short* l) {
  __builtin_amdgcn_global_load_lds(
      (const __attribute__((address_space(1))) uint32_t*)g,
      (__attribute__((address_space(3))) uint32_t*)l, 16, 0, 0);
}

// ---------------- zero accumulators ----------------
__global__ void k_zero(float* imp, float* zsum) {
  if (threadIdx.x < NEXP) imp[threadIdx.x] = 0.f;
  if (threadIdx.x == 0) zsum[0] = 0.f;
}

// ---------------- W1 [E][D][2H] fp32 -> packed W1t [E][2H][D] bf16 ----------------
// R5: vectorized (G13). float4 loads -> fp32 LDS [64][65] -> int4 (8xbf16) stores.
// Old version used scalar 2B stores for 134 MB (~2.5x loss). LDS pad 65 == 1 mod 32:
// store-phase column reads hit banks (8*cc+j+hh)&31, all-distinct -> conflict-free.
__global__ void __launch_bounds__(256) k_conv_w1(const float* __restrict__ W1,
                                                 unsigned short* __restrict__ W1t) {
  __shared__ float tP[2][64][65];     // 33.3 KB
  int h0 = blockIdx.x * 64, d0 = blockIdx.y * 64, e = blockIdx.z;
  int tid = threadIdx.x;
  const float* src = W1 + (size_t)e * DIM * TWO_H;
  for (int i = 0; i < 4; ++i) {
    int g = tid + i * 256;            // float4 index in 64x64 tile
    int dd = g >> 4, c = g & 15;
    float4 a = *(const float4*)&src[(size_t)(d0 + dd) * TWO_H + h0 + c * 4];
    float4 gg = *(const float4*)&src[(size_t)(d0 + dd) * TWO_H + HID + h0 + c * 4];
    *(float4*)&tP[0][dd][c * 4] = a;
    *(float4*)&tP[1][dd][c * 4] = gg;
  }
  __syncthreads();
  unsigned short* dst = W1t + (size_t)e * TWO_H * DIM;
  for (int i = 0; i < 4; ++i) {
    int o = tid + i * 256;            // int4 index among 128 rows x 8 chunks
    int r = o >> 3, cc = o & 7;       // r = 2*hh+p
    int hh = r >> 1, p = r & 1;
    unsigned short pk[8];
#pragma unroll
    for (int j = 0; j < 8; ++j) pk[j] = f2bf(tP[p][cc * 8 + j][hh]);
    *(int4*)&dst[(size_t)(2 * h0 + r) * DIM + d0 + cc * 8] = *(const int4*)pk;
  }
}

// ---------------- W2 [E][H][D] fp32 -> W2t [E][D][H] bf16 (vectorized) ----------------
__global__ void __launch_bounds__(256) k_conv_w2(const float* __restrict__ W2,
                                                 unsigned short* __restrict__ W2t) {
  __shared__ float t[64][65];         // 16.6 KB
  int h0 = blockIdx.x * 64, d0 = blockIdx.y * 64, e = blockIdx.z;
  int tid = threadIdx.x;
  const float* src = W2 + (size_t)e * HID * DIM;
  for (int i = 0; i < 4; ++i) {
    int g = tid + i * 256;
    int hh = g >> 4, c = g & 15;
    *(float4*)&t[hh][c * 4] = *(const float4*)&src[(size_t)(h0 + hh) * DIM + d0 + c * 4];
  }
  __syncthreads();
  unsigned short* dst = W2t + (size_t)e * DIM * HID;
  for (int i = 0; i < 2; ++i) {
    int o = tid + i * 256;            // int4 index among 64 rows x 8 chunks
    int rd = o >> 3, cc = o & 7;
    unsigned short pk[8];
#pragma unroll
    for (int j = 0; j < 8; ++j) pk[j] = f2bf(t[cc * 8 + j][rd]);
    *(int4*)&dst[(size_t)(d0 + rd) * HID + h0 + cc * 8] = *(const int4*)pk;
  }
}

// ---------------- b1 [E][2H] -> packed b1p [E][2H] (pairs a,g) ----------------
__global__ void k_pack_b1(const float* __restrict__ b1, float* __restrict__ b1p) {
  int g = blockIdx.x * blockDim.x + threadIdx.x;
  int e = g >> 13, r = g & (TWO_H - 1);
  int h = r >> 1, p = r & 1;
  b1p[g] = b1[e * TWO_H + p * HID + h];
}

// ---------------- router: 16 tokens/block, block-local reduction ----------------
__global__ void __launch_bounds__(256) k_router(
    const float* __restrict__ x, const float* __restrict__ Wr, const float* __restrict__ br,
    int* __restrict__ idx, float* __restrict__ gate,
    float* __restrict__ imp, float* __restrict__ zsum) {
  __shared__ float sW[TWO_H];          // 32 KB  (Wr is [D][E] = 1024*8)
  __shared__ float sX[16 * 1028];      // 65.8 KB
  __shared__ float sLG[16 * 8];
  __shared__ float sImp[8];
  __shared__ float sZ;
  int tid = threadIdx.x;
  if (tid < 8) sImp[tid] = 0.f;
  if (tid == 8) sZ = 0.f;
  for (int i = 0; i < 8; ++i) {
    int g = tid + i * 256;
    *(float4*)&sW[g * 4] = *(const float4*)&Wr[g * 4];
  }
  int t0 = blockIdx.x * 16;
  const float* xb = x + (size_t)t0 * DIM;
  for (int i = 0; i < 16; ++i) {
    int g = tid + i * 256;           // global float4 index within 16 rows
    int row = g >> 8, c = (g & 255) * 4;
    *(float4*)&sX[row * 1028 + c] = *(const float4*)&xb[(size_t)g * 4];
  }
  __syncthreads();
  int t = tid >> 4, e = (tid >> 1) & 7, half = tid & 1;
  const float* xr = &sX[t * 1028 + half * 512];
  float s = 0.f;
  for (int k = 0; k < 512; k += 4) {
    float4 xv = *(const float4*)&xr[k];
    int kb = (half * 512 + k) * 8 + e;
    s += xv.x * sW[kb] + xv.y * sW[kb + 8] + xv.z * sW[kb + 16] + xv.w * sW[kb + 24];
  }
  s += __shfl_xor(s, 1);               // combine the two K-halves
  if (half == 0) sLG[t * 8 + e] = s + br[e];
  __syncthreads();
  if (tid < 16) {
    int n = t0 + tid;
    float lg[8];
    for (int i = 0; i < 8; ++i) lg[i] = sLG[tid * 8 + i];
    float mx = lg[0];
    for (int i = 1; i < 8; ++i) mx = fmaxf(mx, lg[i]);
    float ex[8], den = 0.f, zs = 0.f;
    for (int i = 0; i < 8; ++i) { ex[i] = __expf(lg[i] - mx); den += ex[i]; zs += lg[i] * lg[i]; }
    atomicAdd(&sZ, zs);
    float rden = 1.f / den;
    for (int i = 0; i < 8; ++i) atomicAdd(&sImp[i], ex[i] * rden);
    int i1 = 0;
    for (int i = 1; i < 8; ++i) if (lg[i] > lg[i1]) i1 = i;     // ties -> lowest idx, like top_k
    int i2 = -1;
    for (int i = 0; i < 8; ++i) { if (i == i1) continue; if (i2 < 0 || lg[i] > lg[i2]) i2 = i; }
    float e2 = __expf(lg[i2] - lg[i1]);
    float g1 = 1.f / (1.f + e2);
    idx[n * 2] = i1; idx[n * 2 + 1] = i2;
    gate[n * 2] = g1; gate[n * 2 + 1] = 1.f - g1;
  }
  __syncthreads();
  if (tid < 8) atomicAdd(&imp[tid], sImp[tid]);
  if (tid == 8) atomicAdd(zsum, sZ);
}

// ---------------- per-expert sequential position scan (flat order s = k*N + n) -----
// R5: stage idx (32 KB) into LDS once (coalesced int4) -> 128-iter scan reads LDS,
// not global (was ~200-600 cyc/iter cross-XCD L2 latency).
__global__ void k_scan(const int* __restrict__ idx, int* __restrict__ pos, int* __restrict__ cnt) {
  __shared__ int sIdx[2 * N_TOK];     // 32 KB
  int tid = threadIdx.x;              // 512
  for (int i = 0; i < 4; ++i)
    ((int4*)sIdx)[tid + i * 512] = ((const int4*)idx)[tid + i * 512];
  __syncthreads();
  int wave = tid >> 6, lane = tid & 63;  // wave == expert id
  int base = 0;
  for (int c = 0; c < (2 * N_TOK) / 64; ++c) {
    int s = c * 64 + lane;
    int n = s & (N_TOK - 1), k = s >> 12;
    int e = sIdx[n * 2 + k];
    unsigned long long m = __ballot(e == wave);
    if (e == wave) pos[s] = base + __popcll(m & ((1ull << lane) - 1ull));
    base += __popcll(m);
  }
  if (lane == 0) cnt[wave] = base;
}

// ---------------- renormalized kept gates ----------------
__global__ void k_weights(const float* __restrict__ gate, const int* __restrict__ pos,
                          float* __restrict__ wn) {
  int n = blockIdx.x * blockDim.x + threadIdx.x;
  if (n >= N_TOK) return;
  float g0 = gate[n * 2], g1 = gate[n * 2 + 1];
  float k0 = (pos[n] < CAP) ? g0 : 0.f;
  float k1 = (pos[N_TOK + n] < CAP) ? g1 : 0.f;
  float den = fmaxf(k0 + k1, 1e-8f);
  wn[n * 2] = k0 / den; wn[n * 2 + 1] = k1 / den;
}

// ---------------- gather + per-expert LayerNorm -> Xn bf16 [E][CAP][D] ----------------
// R5: float4 loads, ushort4 (8B) stores (was scalar 2B stores).
__global__ void __launch_bounds__(256) k_gather_ln(
    const float* __restrict__ x, const float* __restrict__ lns, const float* __restrict__ lnb,
    const int* __restrict__ idx, const int* __restrict__ pos, unsigned short* __restrict__ Xn) {
  int s = blockIdx.x;
  int p = pos[s];
  if (p >= CAP) return;                       // dropped slot (block-uniform exit)
  int n = s & (N_TOK - 1), k = s >> 12;
  int e = idx[n * 2 + k];
  const float* xr = x + (size_t)n * DIM;
  int tid = threadIdx.x;
  float4 v = *(const float4*)&xr[tid * 4];
  float sum = v.x + v.y + v.z + v.w;
  float sq  = v.x * v.x + v.y * v.y + v.z * v.z + v.w * v.w;
  for (int o = 32; o > 0; o >>= 1) { sum += __shfl_down(sum, o); sq += __shfl_down(sq, o); }
  __shared__ float ws[8];
  int wv = tid >> 6, ln = tid & 63;
  if (ln == 0) { ws[wv] = sum; ws[4 + wv] = sq; }
  __syncthreads();
  sum = ws[0] + ws[1] + ws[2] + ws[3];
  sq  = ws[4] + ws[5] + ws[6] + ws[7];
  float mu = sum * (1.f / DIM);
  float var = sq * (1.f / DIM) - mu * mu;
  float rs = rsqrtf(var + 1e-5f);
  unsigned short* orow = Xn + ((size_t)e * CAP + p) * DIM;
  const float* sc = lns + (size_t)e * DIM;
  const float* bi = lnb + (size_t)e * DIM;
  float4 s4 = *(const float4*)&sc[tid * 4];
  float4 b4 = *(const float4*)&bi[tid * 4];
  unsigned short o4[4];
  o4[0] = f2bf((v.x - mu) * rs * s4.x + b4.x);
  o4[1] = f2bf((v.y - mu) * rs * s4.y + b4.y);
  o4[2] = f2bf((v.z - mu) * rs * s4.z + b4.z);
  o4[3] = f2bf((v.w - mu) * rs * s4.w + b4.w);
  *(uint2*)&orow[tid * 4] = *(const uint2*)o4;
}

// ---------------- bf16 MFMA GEMM, 256x256 tile, 8-phase counted-vmcnt schedule ----
// R4 structure (T2+T3+T4+T5, m201 template) + R5: waits deepened vmcnt(4)->vmcnt(6)
// (3 halves in flight; issue->forced-completion = 4 phases ~2800cyc > HBM ~900-1300,
// phase-trace verified: every staged half completes >=1 phase before its read; slot
// write-after-read safety unchanged). Swizzle both-sides (rule #21); T1 XCD swizzle.
template<bool GLU, int M_, int N_, int K_>
__device__ __forceinline__ void gemm_body(
    const unsigned short* __restrict__ A, const unsigned short* __restrict__ B,
    const float* __restrict__ bias, unsigned short* __restrict__ Cout,
    unsigned short* smem) {
  constexpr int KT = K_ / 64;
  constexpr int gx = M_ / 256, gy = N_ / 256;
  constexpr int nwg = gx * gy * NEXP;
  int bid = blockIdx.x + gx * (blockIdx.y + gy * blockIdx.z);
  int lid = (bid & 7) * (nwg >> 3) + (bid >> 3);
  int bm = lid % gx; int rest = lid / gx;
  int e  = rest / gy;
  int m0 = bm * 256, n0 = (rest % gy) * 256;

  const unsigned short* Ae = A + (size_t)e * M_ * K_;
  const unsigned short* Be = B + (size_t)e * N_ * K_;
  int tid = threadIdx.x, lane = tid & 63, wave = tid >> 6;
  int wm = wave >> 2, wn = wave & 3;           // 2 x 4 wave grid
  int quad = lane >> 4, l16 = lane & 15;

  f32x4 acc[8][4];
#pragma unroll
  for (int i = 0; i < 8; ++i)
#pragma unroll
    for (int j = 0; j < 4; ++j) acc[i][j] = f32x4{0.f, 0.f, 0.f, 0.f};

  int ch = (tid & 3) ^ ((tid >> 3) & 3);       // pre-swizzled source chunk
  const unsigned short* Ag0 = Ae + (size_t)(m0 + (tid >> 2)) * K_ + ch * 8;
  const unsigned short* Bg0 = Be + (size_t)(n0 + (tid >> 2)) * K_ + ch * 8;
  unsigned short* sw = smem + wave * 512;      // wave-uniform LDS dest base (shorts)

#define STG(gp, bofs, ks, kh) do {                                   \
    int q_ = (2 * (ks) + (kh)) & 3;                                  \
    int kc_ = (ks) < KT ? (ks) : KT - 1;                             \
    size_t ko_ = (size_t)(kc_ * 64 + (kh) * 32);                     \
    gll16(gp + ko_, sw + (bofs) + q_ * 8192);                        \
    gll16(gp + (size_t)128 * K_ + ko_, sw + (bofs) + q_ * 8192 + 4096); \
  } while (0)

  int chR = quad ^ ((l16 >> 1) & 3);
  const unsigned short* rdA = smem + (wm * 128 + l16) * 32 + chR * 8;
  const unsigned short* rdB = smem + 32768 + (wn * 64 + l16) * 32 + chR * 8;

  bf16x8 aF[4], bF[4];
#define LDB(q) { _Pragma("unroll") for (int nf = 0; nf < 4; ++nf) \
    bF[nf] = *(const bf16x8*)(rdB + (q) * 8192 + nf * 512); }
#define LDA(q, h) { _Pragma("unroll") for (int mf = 0; mf < 4; ++mf) \
    aF[mf] = *(const bf16x8*)(rdA + (q) * 8192 + ((h) * 4 + mf) * 512); }
#define MM(h) { _Pragma("unroll") for (int mf = 0; mf < 4; ++mf) \
    _Pragma("unroll") for (int nf = 0; nf < 4; ++nf) \
    acc[(h)*4+mf][nf] = __builtin_amdgcn_mfma_f32_16x16x32_bf16(aF[mf], bF[nf], acc[(h)*4+mf][nf], 0, 0, 0); }
#define WAIT_LGKM0 { asm volatile("s_waitcnt lgkmcnt(0)" ::: "memory"); __builtin_amdgcn_sched_barrier(0); }
#define WAIT_VM6   { asm volatile("s_waitcnt vmcnt(6)"   ::: "memory"); __builtin_amdgcn_sched_barrier(0); }

  // prologue: stage (0,kh0)(0,kh1)(1,kh0); wait oldest 4 = (0,kh0)
  STG(Ag0, 0, 0, 0); STG(Bg0, 32768, 0, 0);
  STG(Ag0, 0, 0, 1); STG(Bg0, 32768, 0, 1);
  STG(Ag0, 0, 1, 0); STG(Bg0, 32768, 1, 0);
  asm volatile("s_waitcnt vmcnt(8)" ::: "memory");
  __builtin_amdgcn_sched_barrier(0);
  __builtin_amdgcn_s_barrier();

  for (int kt = 0; kt < KT; ++kt) {
    int q0 = (2 * kt) & 3, q1 = (2 * kt + 1) & 3;
    // phase 1: kh0 x m0-3
    LDB(q0); LDA(q0, 0);
    STG(Ag0, 0, kt + 1, 1);
    __builtin_amdgcn_s_barrier();
    WAIT_LGKM0;
    __builtin_amdgcn_s_setprio(1); MM(0); __builtin_amdgcn_s_setprio(0);
    __builtin_amdgcn_s_barrier();
    // phase 2: kh0 x m4-7 (B reused)
    LDA(q0, 1);
    STG(Bg0, 32768, kt + 1, 1);
    WAIT_VM6;
    __builtin_amdgcn_s_barrier();
    WAIT_LGKM0;
    __builtin_amdgcn_s_setprio(1); MM(1); __builtin_amdgcn_s_setprio(0);
    __builtin_amdgcn_s_barrier();
    // phase 3: kh1 x m0-3
    LDB(q1); LDA(q1, 0);
    STG(Ag0, 0, kt + 2, 0);
    __builtin_amdgcn_s_barrier();
    WAIT_LGKM0;
    __builtin_amdgcn_s_setprio(1); MM(0); __builtin_amdgcn_s_setprio(0);
    __builtin_amdgcn_s_barrier();
    // phase 4: kh1 x m4-7
    LDA(q1, 1);
    STG(Bg0, 32768, kt + 2, 0);
    WAIT_VM6;
    __builtin_amdgcn_s_barrier();
    WAIT_LGKM0;
    __builtin_amdgcn_s_setprio(1); MM(1); __builtin_amdgcn_s_setprio(0);
    __builtin_amdgcn_s_barrier();
  }
  asm volatile("s_waitcnt vmcnt(0)" ::: "memory");
  __builtin_amdgcn_sched_barrier(0);
  __builtin_amdgcn_s_barrier();      // LDS free for epilogue reuse

  if (GLU) {
    const float* bp = bias + (size_t)e * TWO_H;
    unsigned short* Ce = Cout + (size_t)e * M_ * (N_ >> 1);
#pragma unroll
    for (int mf = 0; mf < 8; ++mf)
#pragma unroll
      for (int nf = 0; nf < 4; ++nf) {
        int pn = n0 + wn * 64 + nf * 16 + l16;
        float b = bp[pn];
#pragma unroll
        for (int r = 0; r < 4; ++r) {
          int row = wm * 128 + mf * 16 + quad * 4 + r;
          float u = acc[mf][nf][r] + b;
          float g = __shfl_xor(u, 1);          // partner column (pn^1)
          if ((l16 & 1) == 0) {                // even col = a, partner = g
            float vv = u / (1.f + __expf(-g));
            smem[row * 136 + ((wn * 64 + nf * 16 + l16) >> 1)] = f2bf(vv);
          }
        }
      }
    __syncthreads();
    int c = tid & 15, row0 = tid >> 4;         // 0..31
    for (int p = 0; p < 8; ++p) {
      int row = row0 + p * 32;
      *(int4*)&Ce[(size_t)(m0 + row) * (N_ >> 1) + (n0 >> 1) + c * 8] =
          *(const int4*)&smem[row * 136 + c * 8];
    }
  } else {
    unsigned short* Ce = Cout + (size_t)e * M_ * N_;
    for (int h = 0; h < 2; ++h) {
      if (h) __syncthreads();
#pragma unroll
      for (int mf2 = 0; mf2 < 4; ++mf2)
#pragma unroll
        for (int nf = 0; nf < 4; ++nf) {
          int mf = 4 * h + mf2;
          int col = wn * 64 + nf * 16 + l16;
          int lr = wm * 64 + mf2 * 16 + quad * 4;
#pragma unroll
          for (int r = 0; r < 4; ++r)
            smem[(lr + r) * 264 + col] = f2bf(acc[mf][nf][r]);
        }
      __syncthreads();
      int c = tid & 31, row0 = tid >> 5;       // 0..15
      for (int p = 0; p < 8; ++p) {
        int row = row0 + p * 16;               // local 0..127
        int grow = m0 + (row >> 6) * 128 + h * 64 + (row & 63);
        *(int4*)&Ce[(size_t)grow * N_ + n0 + c * 8] =
            *(const int4*)&smem[row * 264 + c * 8];
      }
    }
  }
#undef STG
#undef LDB
#undef LDA
#undef MM
#undef WAIT_LGKM0
#undef WAIT_VM6
}

__global__ void __launch_bounds__(512, 2) k_gemm1(
    const unsigned short* __restrict__ A, const unsigned short* __restrict__ B,
    const float* __restrict__ bias, unsigned short* __restrict__ Cout) {
  __shared__ __align__(16) unsigned short smem[65536];
  gemm_body<true, CAP, TWO_H, DIM>(A, B, bias, Cout, smem);
}
__global__ void __launch_bounds__(512, 2) k_gemm2(
    const unsigned short* __restrict__ A, const unsigned short* __restrict__ B,
    const float* __restrict__ bias, unsigned short* __restrict__ Cout) {
  __shared__ __align__(16) unsigned short smem[65536];
  gemm_body<false, CAP, DIM, HID>(A, B, bias, Cout, smem);
}

// ---------------- combine: y[n] = sum_k w_k * (Yexp[e_k][p_k] + b2[e_k]) ----------------
// R5: vectorized (ushort4 bf16 loads, float4 stores)
__global__ void __launch_bounds__(256) k_gather_out(
    const unsigned short* __restrict__ Yexp, const float* __restrict__ b2,
    const int* __restrict__ idx, const int* __restrict__ pos,
    const float* __restrict__ wn, float* __restrict__ y) {
  int n = blockIdx.x, tid = threadIdx.x;
  int e0 = idx[n * 2], e1 = idx[n * 2 + 1];
  int p0 = min(pos[n], CAP - 1), p1 = min(pos[N_TOK + n], CAP - 1);
  float w0 = wn[n * 2], w1 = wn[n * 2 + 1];
  const unsigned short* r0 = Yexp + ((size_t)e0 * CAP + p0) * DIM;
  const unsigned short* r1 = Yexp + ((size_t)e1 * CAP + p1) * DIM;
  const float* bb0 = b2 + (size_t)e0 * DIM;
  const float* bb1 = b2 + (size_t)e1 * DIM;
  float* yr = y + (size_t)n * DIM;
  int d4 = tid * 4;
  ushort4 a0 = *(const ushort4*)&r0[d4];
  ushort4 a1 = *(const ushort4*)&r1[d4];
  float4 b0 = *(const float4*)&bb0[d4];
  float4 b1 = *(const float4*)&bb1[d4];
  float4 o;
  o.x = w0 * (bf2f(a0.x) + b0.x) + w1 * (bf2f(a1.x) + b1.x);
  o.y = w0 * (bf2f(a0.y) + b0.y) + w1 * (bf2f(a1.y) + b1.y);
  o.z = w0 * (bf2f(a0.z) + b0.z) + w1 * (bf2f(a1.z) + b1.z);
  o.w = w0 * (bf2f(a0.w) + b0.w) + w1 * (bf2f(a1.w) + b1.w);
  *(float4*)&yr[d4] = o;
}

// ---------------- scalar losses ----------------
__global__ void k_losses(const float* __restrict__ imp, const int* __restrict__ cnt,
                         const float* __restrict__ zsum, float* __restrict__ out) {
  if (threadIdx.x != 0 || blockIdx.x != 0) return;
  double li[8], ll[8], mi = 0.0, ml = 0.0;
  for (int i = 0; i < 8; ++i) {
    li[i] = imp[i];
    ll[i] = (double)min(cnt[i], CAP);
    mi += li[i]; ml += ll[i];
  }
  mi /= 8.0; ml /= 8.0;
  double vi = 0.0, vl = 0.0;
  for (int i = 0; i < 8; ++i) { vi += (li[i] - mi) * (li[i] - mi); vl += (ll[i] - ml) * (ll[i] - ml); }
  vi /= 8.0; vl /= 8.0;
  const double eps = 1e-9;
  double cvi = vi / (fmax(mi, eps) * fmax(mi, eps) + eps);
  double cvl = vl / (fmax(ml, eps) * fmax(ml, eps) + eps);
  out[0] = (float)(0.5 * (cvi + cvl));
  out[1] = (float)((double)zsum[0] / (double)(N_TOK * NEXP) * 1e-4);
}

extern "C" void kernel_launch(void* const* d_in, const int* in_sizes, int n_in,
                              void* d_out, int out_size, void* d_ws, size_t ws_size,
                              hipStream_t stream) {
  const float* h   = (const float*)d_in[0];
  const float* Wr  = (const float*)d_in[1];
  const float* br  = (const float*)d_in[2];
  const float* lns = (const float*)d_in[3];
  const float* lnb = (const float*)d_in[4];
  const float* W1  = (const float*)d_in[5];
  const float* b1  = (const float*)d_in[6];
  const float* W2  = (const float*)d_in[7];
  const float* b2  = (const float*)d_in[8];
  float* out = (float*)d_out;

  char* ws = (char*)d_ws;
  size_t off = 0;
  auto alloc = [&](size_t bytes) { char* p = ws + off; off += (bytes + 255) & ~(size_t)255; return p; };
  unsigned short* W1t = (unsigned short*)alloc((size_t)NEXP * TWO_H * DIM * 2);  // 134 MB
  unsigned short* W2t = (unsigned short*)alloc((size_t)NEXP * DIM * HID * 2);    // 67 MB
  unsigned short* Xn  = (unsigned short*)alloc((size_t)NEXP * CAP * DIM * 2);    // 21 MB
  unsigned short* V   = (unsigned short*)alloc((size_t)NEXP * CAP * HID * 2);    // 84 MB
  unsigned short* Yx  = (unsigned short*)alloc((size_t)NEXP * CAP * DIM * 2);    // 21 MB
  float* b1p  = (float*)alloc((size_t)NEXP * TWO_H * 4);
  int*   idx  = (int*)alloc((size_t)N_TOK * 2 * 4);
  float* gate = (float*)alloc((size_t)N_TOK * 2 * 4);
  float* wn   = (float*)alloc((size_t)N_TOK * 2 * 4);
  int*   pos  = (int*)alloc((size_t)2 * N_TOK * 4);
  int*   cnt  = (int*)alloc(64);
  float* imp  = (float*)alloc(64);
  float* zsum = (float*)alloc(64);
  (void)ws_size; (void)in_sizes; (void)n_in; (void)out_size;

  k_zero<<<dim3(1), dim3(64), 0, stream>>>(imp, zsum);
  k_conv_w1<<<dim3(HID / 64, DIM / 64, NEXP), dim3(256), 0, stream>>>(W1, W1t);
  k_conv_w2<<<dim3(HID / 64, DIM / 64, NEXP), dim3(256), 0, stream>>>(W2, W2t);
  k_pack_b1<<<dim3(NEXP * TWO_H / 256), dim3(256), 0, stream>>>(b1, b1p);
  k_router<<<dim3(N_TOK / 16), dim3(256), 0, stream>>>(h, Wr, br, idx, gate, imp, zsum);
  k_scan<<<dim3(1), dim3(512), 0, stream>>>(idx, pos, cnt);
  k_weights<<<dim3(16), dim3(256), 0, stream>>>(gate, pos, wn);
  k_gather_ln<<<dim3(2 * N_TOK), dim3(256), 0, stream>>>(h, lns, lnb, idx, pos, Xn);
  k_gemm1<<<dim3(CAP / 256, TWO_H / 256, NEXP), dim3(512), 0, stream>>>(Xn, W1t, b1p, V);
  k_gemm2<<<dim3(CAP / 256, DIM / 256, NEXP), dim3(512), 0, stream>>>(V, W2t, b1p, Yx);
  k_gather_out<<<dim3(N_TOK), dim3(256), 0, stream>>>(Yx, b2, idx, pos, wn, out);
  k_losses<<<dim3(1), dim3(64), 0, stream>>>(imp, cnt, zsum, out + (size_t)N_TOK * DIM);
}